// Round 3
// baseline (2520.482 us; speedup 1.0000x reference)
//
#include <hip/hip_runtime.h>

#define Nn 100000
#define Ee 800000
#define HC 128
#define HID 32
#define NHD 4
#define EDIM 16
#define Gg 256
#define NOUT 2
#define SLOPE 0.2f
#define BN_EPS 1e-5f

typedef unsigned int u32;

// K[k,col] = sum_j efcW[k,j] * M[l][j,h],  M[l][j,h] = sum_c linE[l][j][h*32+c]*attE[l][h][c]
__global__ void compute_K(const float* __restrict__ efcW, const float* __restrict__ efcb,
                          const float* __restrict__ linE, const float* __restrict__ attE,
                          float* __restrict__ Kmat, float* __restrict__ kb)
{
  int t = threadIdx.x;
  if (t < 192) {
    int k = t / 12, col = t % 12, l = col >> 2, h = col & 3;
    float acc = 0.f;
    for (int j = 0; j < 32; ++j) {
      float m = 0.f;
      for (int c = 0; c < 32; ++c)
        m += linE[(l*32 + j)*128 + h*32 + c] * attE[(l*4 + h)*32 + c];
      acc += efcW[k*32 + j] * m;
    }
    Kmat[k*12 + col] = acc;
  } else if (t < 204) {
    int col = t - 192, l = col >> 2, h = col & 3;
    float acc = 0.f;
    for (int j = 0; j < 32; ++j) {
      float m = 0.f;
      for (int c = 0; c < 32; ++c)
        m += linE[(l*32 + j)*128 + h*32 + c] * attE[(l*4 + h)*32 + c];
      acc += efcb[j] * m;
    }
    kb[col] = acc;
  }
}

// C[N, half*64 .. half*64+63] = A[N,128] @ W[128, cols]; W half staged f32 in 32KB LDS
__global__ __launch_bounds__(256) void gemm_node(const float* __restrict__ A,
                                                 const float* __restrict__ W,
                                                 float* __restrict__ C)
{
  __shared__ float Wsh[HC][64];
  int t = threadIdx.x;
  int half = blockIdx.x & 1;
  // stage: 128 rows x 64 cols = 2048 float4
  for (int i = t; i < HC*16; i += 256) {
    int k = i >> 4, j = i & 15;
    ((float4*)&Wsh[k][0])[j] = ((const float4*)(W + (size_t)k*HC + half*64))[j];
  }
  __syncthreads();
  int cg = t & 15, rl = t >> 4;          // 16 col-groups of 4, 16 rows per tile
  for (int tile = blockIdx.x >> 1; tile < Nn/16; tile += gridDim.x >> 1) {
    int row = tile * 16 + rl;
    const float4* ar = (const float4*)(A + (size_t)row * HC);
    float4 acc = {0.f, 0.f, 0.f, 0.f};
    #pragma unroll 4
    for (int k4 = 0; k4 < 32; ++k4) {
      float4 av = ar[k4];
      #pragma unroll
      for (int r = 0; r < 4; ++r) {
        float4 w = *(const float4*)&Wsh[k4*4 + r][cg*4];
        float a = (r == 0) ? av.x : (r == 1) ? av.y : (r == 2) ? av.z : av.w;
        acc.x += a * w.x; acc.y += a * w.y; acc.z += a * w.z; acc.w += a * w.w;
      }
    }
    *(float4*)(C + (size_t)row * HC + half*64 + cg*4) = acc;
  }
}

__global__ void node_attn(const float* __restrict__ xl, const float* __restrict__ aS,
                          const float* __restrict__ aD,
                          float* __restrict__ as_, float* __restrict__ ad_)
{
  int t = blockIdx.x * 256 + threadIdx.x;
  if (t >= Nn*NHD) return;
  int n = t >> 2, h = t & 3;
  const float4* xr = (const float4*)(xl + (size_t)n * HC + h * HID);
  float s1 = 0.f, s2 = 0.f;
  #pragma unroll
  for (int j = 0; j < 8; ++j) {
    float4 v = xr[j];
    float4 s = *(const float4*)(aS + h * HID + j * 4);
    float4 d = *(const float4*)(aD + h * HID + j * 4);
    s1 += v.x*s.x + v.y*s.y + v.z*s.z + v.w*s.w;
    s2 += v.x*d.x + v.y*d.y + v.z*d.z + v.w*d.w;
  }
  as_[t] = s1; ad_[t] = s2;
}

// alpha -> leakyrelu -> w=exp(alpha) -> denom  (no max-subtract: |alpha| <~ 3, exp-safe)
__global__ void edge_alpha(const int* __restrict__ src, const int* __restrict__ dst,
                           const float* __restrict__ eattr, const float* __restrict__ Kmat,
                           const float* __restrict__ kb, int l,
                           const float* __restrict__ as_, const float* __restrict__ ad_,
                           float* __restrict__ ew, float* __restrict__ denom)
{
  int e = blockIdx.x * 256 + threadIdx.x;
  if (e >= Ee) return;
  const float4* p = (const float4*)(eattr + (size_t)e * EDIM);
  float ea[16];
  #pragma unroll
  for (int q = 0; q < 4; ++q) {
    float4 v = p[q];
    ea[q*4+0] = v.x; ea[q*4+1] = v.y; ea[q*4+2] = v.z; ea[q*4+3] = v.w;
  }
  float al[4];
  #pragma unroll
  for (int h = 0; h < 4; ++h) al[h] = kb[l*4 + h];
  #pragma unroll
  for (int k = 0; k < 16; ++k) {
    float v = ea[k];
    #pragma unroll
    for (int h = 0; h < 4; ++h) al[h] += v * Kmat[k*12 + l*4 + h];
  }
  int s = src[e], d = dst[e];
  float4 sv = *(const float4*)(as_ + (size_t)s * 4);
  float4 dv = *(const float4*)(ad_ + (size_t)d * 4);
  float4 a;
  a.x = al[0] + sv.x + dv.x; a.y = al[1] + sv.y + dv.y;
  a.z = al[2] + sv.z + dv.z; a.w = al[3] + sv.w + dv.w;
  a.x = (a.x > 0.f) ? a.x : SLOPE * a.x;
  a.y = (a.y > 0.f) ? a.y : SLOPE * a.y;
  a.z = (a.z > 0.f) ? a.z : SLOPE * a.z;
  a.w = (a.w > 0.f) ? a.w : SLOPE * a.w;
  float4 w;
  w.x = __expf(a.x); w.y = __expf(a.y); w.z = __expf(a.z); w.w = __expf(a.w);
  *(float4*)(ew + (size_t)e * 4) = w;
  atomicAdd(&denom[d*4+0], w.x);
  atomicAdd(&denom[d*4+1], w.y);
  atomicAdd(&denom[d*4+2], w.z);
  atomicAdd(&denom[d*4+3], w.w);
}

__global__ void edge_pass3(const int* __restrict__ src, const int* __restrict__ dst,
                           const float* __restrict__ ecoef, const float* __restrict__ xl,
                           float* __restrict__ acc)
{
  long long tid = (long long)blockIdx.x * 256 + threadIdx.x;
  if (tid >= (long long)Ee * HC) return;
  int e = (int)(tid >> 7), c = (int)(tid & 127);
  int s = src[e], d = dst[e];
  float w = ecoef[((size_t)e << 2) + (c >> 5)];
  atomicAdd(&acc[(size_t)d * HC + c], w * xl[(size_t)s * HC + c]);
}

__global__ void node_finish(float* __restrict__ acc, const float* __restrict__ denom,
                            const float* __restrict__ bias)
{
  int t = blockIdx.x * 256 + threadIdx.x;
  if (t >= Nn*HC) return;
  int n = t >> 7, c = t & 127;
  float v = acc[t] / (denom[n*4 + (c >> 5)] + 1e-16f) + bias[c];
  acc[t] = v;
}

__global__ void bn_reduce(const float* __restrict__ A, float* __restrict__ bnsum, float* __restrict__ bnsq)
{
  __shared__ float ss[256], sq[256];
  int t = threadIdx.x;
  int c = t & 127, half = t >> 7;
  float s = 0.f, q = 0.f;
  for (int n = blockIdx.x * 2 + half; n < Nn; n += gridDim.x * 2) {
    float v = A[(size_t)n * HC + c];
    s += v; q += v * v;
  }
  ss[t] = s; sq[t] = q;
  __syncthreads();
  if (t < 128) {
    atomicAdd(&bnsum[c], ss[t] + ss[t+128]);
    atomicAdd(&bnsq[c],  sq[t] + sq[t+128]);
  }
}

__global__ void bn_apply(float* __restrict__ A, const float* __restrict__ bnsum,
                         const float* __restrict__ bnsq,
                         const float* __restrict__ gamma, const float* __restrict__ beta)
{
  int t = blockIdx.x * 256 + threadIdx.x;
  if (t >= Nn*HC) return;
  int c = t & 127;
  float mu  = bnsum[c] * (1.f / Nn);
  float var = bnsq[c] * (1.f / Nn) - mu * mu;
  float v = (A[t] - mu) * rsqrtf(var + BN_EPS) * gamma[c] + beta[c];
  A[t] = fmaxf(v, 0.f);
}

__global__ void pool_kernel(const float* __restrict__ A, const int* __restrict__ batch,
                            float* __restrict__ pool)
{
  int t = threadIdx.x;
  int c = t & 127, half = t >> 7;
  int n0 = blockIdx.x * 256;
  float accv = 0.f; int curg = -1;
  for (int i = half; i < 256; i += 2) {
    int n = n0 + i;
    if (n >= Nn) break;
    int g = batch[n];
    if (g != curg) {
      if (curg >= 0) atomicAdd(&pool[(size_t)curg * HC + c], accv);
      curg = g; accv = 0.f;
    }
    accv += A[(size_t)n * HC + c];
  }
  if (curg >= 0) atomicAdd(&pool[(size_t)curg * HC + c], accv);
}

__global__ void cnt_kernel(const int* __restrict__ batch, int* __restrict__ cnt)
{
  int n = blockIdx.x * 256 + threadIdx.x;
  if (n < Nn) atomicAdd(&cnt[batch[n]], 1);
}

__global__ void final_fc(const float* __restrict__ pool, const int* __restrict__ cnt,
                         const float* __restrict__ fcW, const float* __restrict__ fcb,
                         float* __restrict__ out)
{
  int t = blockIdx.x * 256 + threadIdx.x;
  if (t >= Gg * NOUT) return;
  int g = t >> 1, o = t & 1;
  float cn = fmaxf((float)cnt[g], 1.f);
  float acc = 0.f;
  for (int k = 0; k < HC; ++k)
    acc += pool[(size_t)g * HC + k] * fcW[k * NOUT + o];
  out[t] = acc / cn + fcb[o];
}

extern "C" void kernel_launch(void* const* d_in, const int* in_sizes, int n_in,
                              void* d_out, int out_size, void* d_ws, size_t ws_size,
                              hipStream_t stream)
{
  const float* x      = (const float*)d_in[0];
  const int*   eidx   = (const int*)d_in[1];
  const float* eattr  = (const float*)d_in[2];
  const int*   batch  = (const int*)d_in[3];
  const float* efcW   = (const float*)d_in[4];
  const float* efcb   = (const float*)d_in[5];
  const float* Wall   = (const float*)d_in[6];
  const float* attS   = (const float*)d_in[7];
  const float* attD   = (const float*)d_in[8];
  const float* attE   = (const float*)d_in[9];
  const float* linE   = (const float*)d_in[10];
  const float* biases = (const float*)d_in[11];
  const float* gamma  = (const float*)d_in[12];
  const float* beta   = (const float*)d_in[13];
  const float* fcW    = (const float*)d_in[14];
  const float* fcb    = (const float*)d_in[15];
  float* out = (float*)d_out;

  const int* src = eidx;
  const int* dst = eidx + Ee;

  float* ws    = (float*)d_ws;
  float* bufA  = ws;                          // N*128
  float* bufB  = bufA + (size_t)Nn*HC;        // N*128
  float* as_   = bufB + (size_t)Nn*HC;        // N*4
  float* ad_   = as_ + (size_t)Nn*NHD;        // N*4
  float* denom = ad_ + (size_t)Nn*NHD;        // N*4
  float* ew    = denom + (size_t)Nn*NHD;      // E*4
  float* Kmat  = ew + (size_t)Ee*NHD;         // 192
  float* kb    = Kmat + 192;                  // 16 (12 used)
  float* bnsum = kb + 16;                     // 128
  float* bnsq  = bnsum + 128;                 // 128
  float* pool  = bnsq + 128;                  // G*128
  int*   cnt   = (int*)(pool + (size_t)Gg*HC);// G

  compute_K<<<1, 256, 0, stream>>>(efcW, efcb, linE, attE, Kmat, kb);

  for (int l = 0; l < 3; ++l) {
    const float* Ain = (l == 0) ? x : bufA;
    gemm_node<<<2048, 256, 0, stream>>>(Ain, Wall + (size_t)l*HC*HC, bufB);
    node_attn<<<(Nn*NHD + 255)/256, 256, 0, stream>>>(bufB, attS + l*HC, attD + l*HC, as_, ad_);
    hipMemsetAsync(denom, 0, (size_t)Nn*NHD*sizeof(float), stream);
    hipMemsetAsync(bufA, 0, (size_t)Nn*HC*sizeof(float), stream);
    edge_alpha<<<(Ee + 255)/256, 256, 0, stream>>>(src, dst, eattr, Kmat, kb, l, as_, ad_, ew, denom);
    edge_pass3<<<(Ee*HC)/256, 256, 0, stream>>>(src, dst, ew, bufB, bufA);
    node_finish<<<(Nn*HC + 255)/256, 256, 0, stream>>>(bufA, denom, biases + l*HC);
    hipMemsetAsync(bnsum, 0, 256*sizeof(float), stream);
    bn_reduce<<<256, 256, 0, stream>>>(bufA, bnsum, bnsq);
    bn_apply<<<(Nn*HC + 255)/256, 256, 0, stream>>>(bufA, bnsum, bnsq, gamma + l*HC, beta + l*HC);
  }

  hipMemsetAsync(pool, 0, (size_t)Gg*HC*sizeof(float), stream);
  hipMemsetAsync(cnt, 0, Gg*sizeof(int), stream);
  pool_kernel<<<(Nn + 255)/256, 256, 0, stream>>>(bufA, batch, pool);
  cnt_kernel<<<(Nn + 255)/256, 256, 0, stream>>>(batch, cnt);
  final_fc<<<2, 256, 0, stream>>>(pool, cnt, fcW, fcb, out);
}

// Round 5
// 1673.312 us; speedup vs baseline: 1.5063x; 1.5063x over previous
//
#include <hip/hip_runtime.h>

#define Nn 100000
#define Ee 800000
#define HC 128
#define HID 32
#define NHD 4
#define EDIM 16
#define Gg 256
#define NOUT 2
#define SLOPE 0.2f
#define BN_EPS 1e-5f
#define SCHUNK 1024
#define NSB 98   // ceil(Nn/SCHUNK)

typedef unsigned int u32;

// ---- tiny weight precompute: Kmat[16][12], kb[12]  (edge-path algebraic fold) ----
__global__ void compute_K(const float* __restrict__ efcW, const float* __restrict__ efcb,
                          const float* __restrict__ linE, const float* __restrict__ attE,
                          float* __restrict__ Kmat, float* __restrict__ kb)
{
  __shared__ float Msh[384];   // M[l][j][h] = sum_c linE[l][j][h*32+c]*attE[l][h][c]
  int t = threadIdx.x;
  if (t < 384) {
    int l = t >> 7, j = (t >> 2) & 31, h = t & 3;
    float m = 0.f;
    for (int c = 0; c < 32; ++c)
      m += linE[(l*32 + j)*128 + h*32 + c] * attE[(l*4 + h)*32 + c];
    Msh[l*128 + j*4 + h] = m;
  }
  __syncthreads();
  if (t < 192) {
    int k = t / 12, col = t % 12, l = col >> 2, h = col & 3;
    float acc = 0.f;
    for (int j = 0; j < 32; ++j)
      acc += efcW[k*32 + j] * Msh[l*128 + j*4 + h];
    Kmat[k*12 + col] = acc;
  } else if (t < 204) {
    int col = t - 192, l = col >> 2, h = col & 3;
    float acc = 0.f;
    for (int j = 0; j < 32; ++j)
      acc += efcb[j] * Msh[l*128 + j*4 + h];
    kb[col] = acc;
  }
}

// ---- CSR build ----
__global__ void k_hist(const int* __restrict__ dst, int* __restrict__ deg)
{
  int e = blockIdx.x * 256 + threadIdx.x;
  if (e < Ee) atomicAdd(&deg[dst[e]], 1);
}

__global__ void k_bsum(const int* __restrict__ deg, int* __restrict__ bsum)
{
  __shared__ int sh[256];
  int b = blockIdx.x, t = threadIdx.x;
  int s = 0;
  for (int i = t; i < SCHUNK; i += 256) {
    int idx = b*SCHUNK + i;
    if (idx < Nn) s += deg[idx];
  }
  sh[t] = s; __syncthreads();
  for (int o = 128; o; o >>= 1) { if (t < o) sh[t] += sh[t+o]; __syncthreads(); }
  if (!t) bsum[b] = sh[0];
}

__global__ void k_mid(const int* __restrict__ bsum, int* __restrict__ bpre, int* __restrict__ rowp)
{
  __shared__ int sh[NSB];
  int t = threadIdx.x;
  if (t < NSB) sh[t] = bsum[t];
  __syncthreads();
  if (!t) {
    int run = 0;
    for (int i = 0; i < NSB; ++i) { int v = sh[i]; sh[i] = run; run += v; }
    rowp[Nn] = run;
  }
  __syncthreads();
  if (t < NSB) bpre[t] = sh[t];
}

__global__ void k_scan(const int* __restrict__ deg, const int* __restrict__ bpre, int* __restrict__ rowp)
{
  __shared__ int sh[SCHUNK];
  int b = blockIdx.x, t = threadIdx.x;
  for (int i = t; i < SCHUNK; i += 256) {
    int idx = b*SCHUNK + i;
    sh[i] = (idx < Nn) ? deg[idx] : 0;
  }
  __syncthreads();
  if (!t) {
    int run = 0;
    for (int i = 0; i < SCHUNK; ++i) { int v = sh[i]; sh[i] = run; run += v; }
  }
  __syncthreads();
  int base = bpre[b];
  for (int i = t; i < SCHUNK; i += 256) {
    int idx = b*SCHUNK + i;
    if (idx < Nn) rowp[idx] = sh[i] + base;
  }
}

__global__ void k_fill(const int* __restrict__ src, const int* __restrict__ dst,
                       const int* __restrict__ rowp, int* __restrict__ fill,
                       int* __restrict__ src_s, int* __restrict__ perm)
{
  int e = blockIdx.x * 256 + threadIdx.x;
  if (e >= Ee) return;
  int d = dst[e];
  int pos = rowp[d] + atomicAdd(&fill[d], 1);
  src_s[pos] = src[e];
  perm[e] = pos;
}

// ---- GEMM: C[N,128] = A[N,128] @ W[128,128]
// 256 thr; block does 128 rows x 64 cols (hf = col half); W half in LDS (34 KB, +4 pad);
// A streamed from global (8-thread reuse per float4 via L1). 4x8 accum/thread.
__global__ __launch_bounds__(256) void gemm_node(const float* __restrict__ A,
                                                 const float* __restrict__ W,
                                                 float* __restrict__ C)
{
  __shared__ float Wh[HC][68];   // 128 rows x 64 cols staged, stride 68
  int t = threadIdx.x;
  int hf = blockIdx.x & 1;
  int row0 = (blockIdx.x >> 1) * 128;
  for (int i = t; i < HC*16; i += 256) {
    int k = i >> 4, c4 = i & 15;
    *(float4*)&Wh[k][c4*4] = *(const float4*)(W + (size_t)k*HC + hf*64 + c4*4);
  }
  __syncthreads();
  int m = t & 31, g = t >> 5;   // rows m+32i (i<4), cols g*8..g*8+7
  int rows[4];
  #pragma unroll
  for (int i = 0; i < 4; ++i) {
    int r = row0 + m + 32*i;
    rows[i] = (r < Nn) ? r : (Nn - 1);
  }
  float4 acc[4][2];
  #pragma unroll
  for (int i = 0; i < 4; ++i) {
    acc[i][0] = make_float4(0.f,0.f,0.f,0.f);
    acc[i][1] = make_float4(0.f,0.f,0.f,0.f);
  }
  for (int k4 = 0; k4 < 32; ++k4) {
    float4 a[4];
    #pragma unroll
    for (int i = 0; i < 4; ++i)
      a[i] = *(const float4*)(A + (size_t)rows[i]*HC + k4*4);
    float4 w0[4], w1[4];
    #pragma unroll
    for (int j = 0; j < 4; ++j) {
      w0[j] = *(const float4*)&Wh[k4*4 + j][g*8];
      w1[j] = *(const float4*)&Wh[k4*4 + j][g*8 + 4];
    }
    #pragma unroll
    for (int i = 0; i < 4; ++i) {
      float4 av = a[i];
      acc[i][0].x += av.x*w0[0].x + av.y*w0[1].x + av.z*w0[2].x + av.w*w0[3].x;
      acc[i][0].y += av.x*w0[0].y + av.y*w0[1].y + av.z*w0[2].y + av.w*w0[3].y;
      acc[i][0].z += av.x*w0[0].z + av.y*w0[1].z + av.z*w0[2].z + av.w*w0[3].z;
      acc[i][0].w += av.x*w0[0].w + av.y*w0[1].w + av.z*w0[2].w + av.w*w0[3].w;
      acc[i][1].x += av.x*w1[0].x + av.y*w1[1].x + av.z*w1[2].x + av.w*w1[3].x;
      acc[i][1].y += av.x*w1[0].y + av.y*w1[1].y + av.z*w1[2].y + av.w*w1[3].y;
      acc[i][1].z += av.x*w1[0].z + av.y*w1[1].z + av.z*w1[2].z + av.w*w1[3].z;
      acc[i][1].w += av.x*w1[0].w + av.y*w1[1].w + av.z*w1[2].w + av.w*w1[3].w;
    }
  }
  #pragma unroll
  for (int i = 0; i < 4; ++i) {
    int row = row0 + m + 32*i;
    if (row < Nn) {
      *(float4*)(C + (size_t)row*HC + hf*64 + g*8)     = acc[i][0];
      *(float4*)(C + (size_t)row*HC + hf*64 + g*8 + 4) = acc[i][1];
    }
  }
}

__global__ void node_attn(const float* __restrict__ xl, const float* __restrict__ aS,
                          const float* __restrict__ aD,
                          float* __restrict__ as_, float* __restrict__ ad_)
{
  int t = blockIdx.x * 256 + threadIdx.x;
  if (t >= Nn*NHD) return;
  int n = t >> 2, h = t & 3;
  const float4* xr = (const float4*)(xl + (size_t)n * HC + h * HID);
  float s1 = 0.f, s2 = 0.f;
  #pragma unroll
  for (int j = 0; j < 8; ++j) {
    float4 v = xr[j];
    float4 s = *(const float4*)(aS + h * HID + j * 4);
    float4 d = *(const float4*)(aD + h * HID + j * 4);
    s1 += v.x*s.x + v.y*s.y + v.z*s.z + v.w*s.w;
    s2 += v.x*d.x + v.y*d.y + v.z*d.z + v.w*d.w;
  }
  as_[t] = s1; ad_[t] = s2;
}

// alpha -> leaky -> w=exp(alpha), scattered into dst-sorted position
__global__ void edge_alpha(const int* __restrict__ src, const int* __restrict__ dst,
                           const float* __restrict__ eattr, const float* __restrict__ Kmat,
                           const float* __restrict__ kb, int l,
                           const float* __restrict__ as_, const float* __restrict__ ad_,
                           const int* __restrict__ perm, float* __restrict__ ew_s)
{
  int e = blockIdx.x * 256 + threadIdx.x;
  if (e >= Ee) return;
  const float4* p = (const float4*)(eattr + (size_t)e * EDIM);
  float ea[16];
  #pragma unroll
  for (int q = 0; q < 4; ++q) {
    float4 v = p[q];
    ea[q*4+0] = v.x; ea[q*4+1] = v.y; ea[q*4+2] = v.z; ea[q*4+3] = v.w;
  }
  float al[4];
  #pragma unroll
  for (int h = 0; h < 4; ++h) al[h] = kb[l*4 + h];
  #pragma unroll
  for (int k = 0; k < 16; ++k) {
    float v = ea[k];
    #pragma unroll
    for (int h = 0; h < 4; ++h) al[h] += v * Kmat[k*12 + l*4 + h];
  }
  int s = src[e], d = dst[e];
  float4 sv = *(const float4*)(as_ + (size_t)s * 4);
  float4 dv = *(const float4*)(ad_ + (size_t)d * 4);
  float4 a;
  a.x = al[0] + sv.x + dv.x; a.y = al[1] + sv.y + dv.y;
  a.z = al[2] + sv.z + dv.z; a.w = al[3] + sv.w + dv.w;
  a.x = (a.x > 0.f) ? a.x : SLOPE * a.x;
  a.y = (a.y > 0.f) ? a.y : SLOPE * a.y;
  a.z = (a.z > 0.f) ? a.z : SLOPE * a.z;
  a.w = (a.w > 0.f) ? a.w : SLOPE * a.w;
  float4 w;
  w.x = __expf(a.x); w.y = __expf(a.y); w.z = __expf(a.z); w.w = __expf(a.w);
  int pos = perm[e];
  *(float4*)(ew_s + (size_t)pos * 4) = w;
}

// CSR aggregation: 2 nodes per block; softmax-normalize + bias fused
__global__ __launch_bounds__(256) void aggregate(const int* __restrict__ rowp, const int* __restrict__ src_s,
                                                 const float* __restrict__ ew_s, const float* __restrict__ xl,
                                                 const float* __restrict__ bias, float* __restrict__ outp)
{
  int n = blockIdx.x * 2 + (threadIdx.x >> 7);
  if (n >= Nn) return;
  int c = threadIdx.x & 127;
  int h = c >> 5;
  int beg = rowp[n], end = rowp[n+1];
  float acc = 0.f, wsum = 0.f;
  for (int i = beg; i < end; ++i) {
    int s = src_s[i];
    float w = ew_s[(size_t)i*4 + h];
    acc += w * xl[(size_t)s * HC + c];
    wsum += w;
  }
  outp[(size_t)n * HC + c] = acc / (wsum + 1e-16f) + bias[c];
}

__global__ void bn_reduce(const float* __restrict__ A, float* __restrict__ bnsum, float* __restrict__ bnsq)
{
  __shared__ float ss[256], sq[256];
  int t = threadIdx.x;
  int c = t & 127, hh = t >> 7;
  float s = 0.f, q = 0.f;
  for (int n = blockIdx.x * 2 + hh; n < Nn; n += gridDim.x * 2) {
    float v = A[(size_t)n * HC + c];
    s += v; q += v * v;
  }
  ss[t] = s; sq[t] = q;
  __syncthreads();
  if (t < 128) {
    atomicAdd(&bnsum[c], ss[t] + ss[t+128]);
    atomicAdd(&bnsq[c],  sq[t] + sq[t+128]);
  }
}

__global__ void bn_apply(float* __restrict__ A, const float* __restrict__ bnsum,
                         const float* __restrict__ bnsq,
                         const float* __restrict__ gamma, const float* __restrict__ beta)
{
  int t = blockIdx.x * 256 + threadIdx.x;
  if (t >= Nn*HC) return;
  int c = t & 127;
  float mu  = bnsum[c] * (1.f / Nn);
  float var = bnsq[c] * (1.f / Nn) - mu * mu;
  float v = (A[t] - mu) * rsqrtf(var + BN_EPS) * gamma[c] + beta[c];
  A[t] = fmaxf(v, 0.f);
}

__global__ void pool_kernel(const float* __restrict__ A, const int* __restrict__ batch,
                            float* __restrict__ pool)
{
  int t = threadIdx.x;
  int c = t & 127, hh = t >> 7;
  int n0 = blockIdx.x * 256;
  float accv = 0.f; int curg = -1;
  for (int i = hh; i < 256; i += 2) {
    int n = n0 + i;
    if (n >= Nn) break;
    int g = batch[n];
    if (g != curg) {
      if (curg >= 0) atomicAdd(&pool[(size_t)curg * HC + c], accv);
      curg = g; accv = 0.f;
    }
    accv += A[(size_t)n * HC + c];
  }
  if (curg >= 0) atomicAdd(&pool[(size_t)curg * HC + c], accv);
}

__global__ void cnt_kernel(const int* __restrict__ batch, int* __restrict__ cnt)
{
  int n = blockIdx.x * 256 + threadIdx.x;
  if (n < Nn) atomicAdd(&cnt[batch[n]], 1);
}

__global__ void final_fc(const float* __restrict__ pool, const int* __restrict__ cnt,
                         const float* __restrict__ fcW, const float* __restrict__ fcb,
                         float* __restrict__ out)
{
  int t = blockIdx.x * 256 + threadIdx.x;
  if (t >= Gg * NOUT) return;
  int g = t >> 1, o = t & 1;
  float cn = fmaxf((float)cnt[g], 1.f);
  float acc = 0.f;
  for (int k = 0; k < HC; ++k)
    acc += pool[(size_t)g * HC + k] * fcW[k * NOUT + o];
  out[t] = acc / cn + fcb[o];
}

extern "C" void kernel_launch(void* const* d_in, const int* in_sizes, int n_in,
                              void* d_out, int out_size, void* d_ws, size_t ws_size,
                              hipStream_t stream)
{
  const float* x      = (const float*)d_in[0];
  const int*   eidx   = (const int*)d_in[1];
  const float* eattr  = (const float*)d_in[2];
  const int*   batch  = (const int*)d_in[3];
  const float* efcW   = (const float*)d_in[4];
  const float* efcb   = (const float*)d_in[5];
  const float* Wall   = (const float*)d_in[6];
  const float* attS   = (const float*)d_in[7];
  const float* attD   = (const float*)d_in[8];
  const float* attE   = (const float*)d_in[9];
  const float* linE   = (const float*)d_in[10];
  const float* biases = (const float*)d_in[11];
  const float* gamma  = (const float*)d_in[12];
  const float* beta   = (const float*)d_in[13];
  const float* fcW    = (const float*)d_in[14];
  const float* fcb    = (const float*)d_in[15];
  float* out = (float*)d_out;

  const int* src = eidx;
  const int* dst = eidx + Ee;

  float* ws    = (float*)d_ws;
  float* bufA  = ws;                            // N*128
  float* bufB  = bufA + (size_t)Nn*HC;          // N*128
  float* as_   = bufB + (size_t)Nn*HC;          // N*4
  float* ad_   = as_ + (size_t)Nn*NHD;          // N*4
  float* ew_s  = ad_ + (size_t)Nn*NHD;          // E*4 (16B aligned)
  float* Kmat  = ew_s + (size_t)Ee*NHD;         // 192
  float* kb    = Kmat + 192;                    // 16
  float* bnsum = kb + 16;                       // 128
  float* bnsq  = bnsum + 128;                   // 128
  float* pool  = bnsq + 128;                    // G*128
  int*   cnt   = (int*)(pool + (size_t)Gg*HC);  // G
  int*   rowp  = cnt + Gg;                      // N+1
  int*   deg   = rowp + (Nn + 1);               // N
  int*   fill  = deg + Nn;                      // N  (deg..fill one memset)
  int*   src_s = fill + Nn;                     // E
  int*   perm  = src_s + Ee;                    // E
  int*   bsum  = perm + Ee;                     // NSB
  int*   bpre  = bsum + 128;                    // NSB

  compute_K<<<1, 512, 0, stream>>>(efcW, efcb, linE, attE, Kmat, kb);

  // CSR build (reused across all 3 layers)
  hipMemsetAsync(deg, 0, 2*Nn*sizeof(int), stream);
  k_hist<<<(Ee + 255)/256, 256, 0, stream>>>(dst, deg);
  k_bsum<<<NSB, 256, 0, stream>>>(deg, bsum);
  k_mid<<<1, 128, 0, stream>>>(bsum, bpre, rowp);
  k_scan<<<NSB, 256, 0, stream>>>(deg, bpre, rowp);
  k_fill<<<(Ee + 255)/256, 256, 0, stream>>>(src, dst, rowp, fill, src_s, perm);

  for (int l = 0; l < 3; ++l) {
    const float* Ain = (l == 0) ? x : bufA;
    gemm_node<<<((Nn + 127)/128)*2, 256, 0, stream>>>(Ain, Wall + (size_t)l*HC*HC, bufB);
    node_attn<<<(Nn*NHD + 255)/256, 256, 0, stream>>>(bufB, attS + l*HC, attD + l*HC, as_, ad_);
    edge_alpha<<<(Ee + 255)/256, 256, 0, stream>>>(src, dst, eattr, Kmat, kb, l, as_, ad_, perm, ew_s);
    aggregate<<<(Nn + 1)/2, 256, 0, stream>>>(rowp, src_s, ew_s, bufB, biases + l*HC, bufA);
    hipMemsetAsync(bnsum, 0, 256*sizeof(float), stream);
    bn_reduce<<<256, 256, 0, stream>>>(bufA, bnsum, bnsq);
    bn_apply<<<(Nn*HC + 255)/256, 256, 0, stream>>>(bufA, bnsum, bnsq, gamma + l*HC, beta + l*HC);
  }

  hipMemsetAsync(pool, 0, ((size_t)Gg*HC)*sizeof(float) + Gg*sizeof(int), stream);
  pool_kernel<<<(Nn + 255)/256, 256, 0, stream>>>(bufA, batch, pool);
  cnt_kernel<<<(Nn + 255)/256, 256, 0, stream>>>(batch, cnt);
  final_fc<<<2, 256, 0, stream>>>(pool, cnt, fcW, fcb, out);
}

// Round 6
// 1251.753 us; speedup vs baseline: 2.0136x; 1.3368x over previous
//
#include <hip/hip_runtime.h>

#define Nn 100000
#define Ee 800000
#define HC 128
#define HID 32
#define NHD 4
#define EDIM 16
#define Gg 256
#define NOUT 2
#define SLOPE 0.2f
#define BN_EPS 1e-5f
#define SCHUNK 1024
#define NSB 98   // ceil(Nn/SCHUNK)

typedef unsigned int u32;

// ---- tiny weight precompute: Kmat[16][12], kb[12]  (edge-path algebraic fold) ----
__global__ void compute_K(const float* __restrict__ efcW, const float* __restrict__ efcb,
                          const float* __restrict__ linE, const float* __restrict__ attE,
                          float* __restrict__ Kmat, float* __restrict__ kb)
{
  __shared__ float Msh[384];   // M[l][j][h] = sum_c linE[l][j][h*32+c]*attE[l][h][c]
  int t = threadIdx.x;
  if (t < 384) {
    int l = t >> 7, j = (t >> 2) & 31, h = t & 3;
    float m = 0.f;
    for (int c = 0; c < 32; ++c)
      m += linE[(l*32 + j)*128 + h*32 + c] * attE[(l*4 + h)*32 + c];
    Msh[l*128 + j*4 + h] = m;
  }
  __syncthreads();
  if (t < 192) {
    int k = t / 12, col = t % 12, l = col >> 2, h = col & 3;
    float acc = 0.f;
    for (int j = 0; j < 32; ++j)
      acc += efcW[k*32 + j] * Msh[l*128 + j*4 + h];
    Kmat[k*12 + col] = acc;
  } else if (t < 204) {
    int col = t - 192, l = col >> 2, h = col & 3;
    float acc = 0.f;
    for (int j = 0; j < 32; ++j)
      acc += efcb[j] * Msh[l*128 + j*4 + h];
    kb[col] = acc;
  }
}

// ---- CSR build ----
__global__ void k_hist(const int* __restrict__ dst, int* __restrict__ deg)
{
  int e = blockIdx.x * 256 + threadIdx.x;
  if (e < Ee) atomicAdd(&deg[dst[e]], 1);
}

__global__ void k_bsum(const int* __restrict__ deg, int* __restrict__ bsum)
{
  __shared__ int sh[256];
  int b = blockIdx.x, t = threadIdx.x;
  int s = 0;
  for (int i = t; i < SCHUNK; i += 256) {
    int idx = b*SCHUNK + i;
    if (idx < Nn) s += deg[idx];
  }
  sh[t] = s; __syncthreads();
  for (int o = 128; o; o >>= 1) { if (t < o) sh[t] += sh[t+o]; __syncthreads(); }
  if (!t) bsum[b] = sh[0];
}

__global__ void k_mid(const int* __restrict__ bsum, int* __restrict__ bpre, int* __restrict__ rowp)
{
  __shared__ int sh[NSB];
  int t = threadIdx.x;
  if (t < NSB) sh[t] = bsum[t];
  __syncthreads();
  if (!t) {
    int run = 0;
    for (int i = 0; i < NSB; ++i) { int v = sh[i]; sh[i] = run; run += v; }
    rowp[Nn] = run;
  }
  __syncthreads();
  if (t < NSB) bpre[t] = sh[t];
}

__global__ void k_scan(const int* __restrict__ deg, const int* __restrict__ bpre, int* __restrict__ rowp)
{
  __shared__ int sh[SCHUNK];
  int b = blockIdx.x, t = threadIdx.x;
  for (int i = t; i < SCHUNK; i += 256) {
    int idx = b*SCHUNK + i;
    sh[i] = (idx < Nn) ? deg[idx] : 0;
  }
  __syncthreads();
  if (!t) {
    int run = 0;
    for (int i = 0; i < SCHUNK; ++i) { int v = sh[i]; sh[i] = run; run += v; }
  }
  __syncthreads();
  int base = bpre[b];
  for (int i = t; i < SCHUNK; i += 256) {
    int idx = b*SCHUNK + i;
    if (idx < Nn) rowp[idx] = sh[i] + base;
  }
}

__global__ void k_fill(const int* __restrict__ src, const int* __restrict__ dst,
                       const int* __restrict__ rowp, int* __restrict__ fill,
                       int* __restrict__ src_s, int* __restrict__ perm)
{
  int e = blockIdx.x * 256 + threadIdx.x;
  if (e >= Ee) return;
  int d = dst[e];
  int pos = rowp[d] + atomicAdd(&fill[d], 1);
  src_s[pos] = src[e];
  perm[e] = pos;
}

// ---- GEMM: C[N,128] = BN?(A[N,128]) @ W[128,128]
// 256 thr; block = 128 rows x 64 cols (hf). Lane map: cg=t&7 (8 col-groups of 8),
// r=t>>3 (rows r+32i) -> A-load instr spans 8 lines (coalesced). W half in LDS.
// BN+ReLU of previous layer applied on A load (scale/shift from LDS).
__global__ __launch_bounds__(256) void gemm_node(const float* __restrict__ A,
                                                 const float* __restrict__ W,
                                                 float* __restrict__ C,
                                                 const float* __restrict__ bnsum,
                                                 const float* __restrict__ bnsq,
                                                 const float* __restrict__ gammaL,
                                                 const float* __restrict__ betaL,
                                                 int apply_bn)
{
  __shared__ float Wh[HC][68];   // 128 k x 64 cols staged, stride 68
  __shared__ float sc_[HC], sh_[HC];
  int t = threadIdx.x;
  int hf = blockIdx.x & 1;
  int row0 = (blockIdx.x >> 1) * 128;
  for (int i = t; i < HC*16; i += 256) {
    int k = i >> 4, c4 = i & 15;
    *(float4*)&Wh[k][c4*4] = *(const float4*)(W + (size_t)k*HC + hf*64 + c4*4);
  }
  if (t < HC) {
    if (apply_bn) {
      float mu  = bnsum[t] * (1.f / Nn);
      float var = bnsq[t] * (1.f / Nn) - mu * mu;
      float s = rsqrtf(var + BN_EPS) * gammaL[t];
      sc_[t] = s;
      sh_[t] = betaL[t] - mu * s;
    } else { sc_[t] = 1.f; sh_[t] = 0.f; }
  }
  __syncthreads();
  int cg = t & 7, r = t >> 3;   // cols hf*64 + cg*8 .. +7 ; rows r+32i
  int rows[4];
  #pragma unroll
  for (int i = 0; i < 4; ++i) {
    int rr = row0 + r + 32*i;
    rows[i] = (rr < Nn) ? rr : (Nn - 1);
  }
  float4 acc[4][2];
  #pragma unroll
  for (int i = 0; i < 4; ++i) {
    acc[i][0] = make_float4(0.f,0.f,0.f,0.f);
    acc[i][1] = make_float4(0.f,0.f,0.f,0.f);
  }
  if (apply_bn) {
    for (int k4 = 0; k4 < 32; ++k4) {
      float4 s4 = *(const float4*)&sc_[k4*4];
      float4 h4 = *(const float4*)&sh_[k4*4];
      float4 a[4];
      #pragma unroll
      for (int i = 0; i < 4; ++i) {
        float4 v = *(const float4*)(A + (size_t)rows[i]*HC + k4*4);
        v.x = fmaxf(v.x*s4.x + h4.x, 0.f);
        v.y = fmaxf(v.y*s4.y + h4.y, 0.f);
        v.z = fmaxf(v.z*s4.z + h4.z, 0.f);
        v.w = fmaxf(v.w*s4.w + h4.w, 0.f);
        a[i] = v;
      }
      float4 w0[4], w1[4];
      #pragma unroll
      for (int j = 0; j < 4; ++j) {
        w0[j] = *(const float4*)&Wh[k4*4 + j][cg*8];
        w1[j] = *(const float4*)&Wh[k4*4 + j][cg*8 + 4];
      }
      #pragma unroll
      for (int i = 0; i < 4; ++i) {
        float4 av = a[i];
        acc[i][0].x += av.x*w0[0].x + av.y*w0[1].x + av.z*w0[2].x + av.w*w0[3].x;
        acc[i][0].y += av.x*w0[0].y + av.y*w0[1].y + av.z*w0[2].y + av.w*w0[3].y;
        acc[i][0].z += av.x*w0[0].z + av.y*w0[1].z + av.z*w0[2].z + av.w*w0[3].z;
        acc[i][0].w += av.x*w0[0].w + av.y*w0[1].w + av.z*w0[2].w + av.w*w0[3].w;
        acc[i][1].x += av.x*w1[0].x + av.y*w1[1].x + av.z*w1[2].x + av.w*w1[3].x;
        acc[i][1].y += av.x*w1[0].y + av.y*w1[1].y + av.z*w1[2].y + av.w*w1[3].y;
        acc[i][1].z += av.x*w1[0].z + av.y*w1[1].z + av.z*w1[2].z + av.w*w1[3].z;
        acc[i][1].w += av.x*w1[0].w + av.y*w1[1].w + av.z*w1[2].w + av.w*w1[3].w;
      }
    }
  } else {
    for (int k4 = 0; k4 < 32; ++k4) {
      float4 a[4];
      #pragma unroll
      for (int i = 0; i < 4; ++i)
        a[i] = *(const float4*)(A + (size_t)rows[i]*HC + k4*4);
      float4 w0[4], w1[4];
      #pragma unroll
      for (int j = 0; j < 4; ++j) {
        w0[j] = *(const float4*)&Wh[k4*4 + j][cg*8];
        w1[j] = *(const float4*)&Wh[k4*4 + j][cg*8 + 4];
      }
      #pragma unroll
      for (int i = 0; i < 4; ++i) {
        float4 av = a[i];
        acc[i][0].x += av.x*w0[0].x + av.y*w0[1].x + av.z*w0[2].x + av.w*w0[3].x;
        acc[i][0].y += av.x*w0[0].y + av.y*w0[1].y + av.z*w0[2].y + av.w*w0[3].y;
        acc[i][0].z += av.x*w0[0].z + av.y*w0[1].z + av.z*w0[2].z + av.w*w0[3].z;
        acc[i][0].w += av.x*w0[0].w + av.y*w0[1].w + av.z*w0[2].w + av.w*w0[3].w;
        acc[i][1].x += av.x*w1[0].x + av.y*w1[1].x + av.z*w1[2].x + av.w*w1[3].x;
        acc[i][1].y += av.x*w1[0].y + av.y*w1[1].y + av.z*w1[2].y + av.w*w1[3].y;
        acc[i][1].z += av.x*w1[0].z + av.y*w1[1].z + av.z*w1[2].z + av.w*w1[3].z;
        acc[i][1].w += av.x*w1[0].w + av.y*w1[1].w + av.z*w1[2].w + av.w*w1[3].w;
      }
    }
  }
  #pragma unroll
  for (int i = 0; i < 4; ++i) {
    int row = row0 + r + 32*i;
    if (row < Nn) {
      *(float4*)(C + (size_t)row*HC + hf*64 + cg*8)     = acc[i][0];
      *(float4*)(C + (size_t)row*HC + hf*64 + cg*8 + 4) = acc[i][1];
    }
  }
}

__global__ void node_attn(const float* __restrict__ xl, const float* __restrict__ aS,
                          const float* __restrict__ aD,
                          float* __restrict__ as_, float* __restrict__ ad_)
{
  int t = blockIdx.x * 256 + threadIdx.x;
  if (t >= Nn*NHD) return;
  int n = t >> 2, h = t & 3;
  const float4* xr = (const float4*)(xl + (size_t)n * HC + h * HID);
  float s1 = 0.f, s2 = 0.f;
  #pragma unroll
  for (int j = 0; j < 8; ++j) {
    float4 v = xr[j];
    float4 s = *(const float4*)(aS + h * HID + j * 4);
    float4 d = *(const float4*)(aD + h * HID + j * 4);
    s1 += v.x*s.x + v.y*s.y + v.z*s.z + v.w*s.w;
    s2 += v.x*d.x + v.y*d.y + v.z*d.z + v.w*d.w;
  }
  as_[t] = s1; ad_[t] = s2;
}

// alpha -> leaky -> w=exp(alpha), scattered into dst-sorted position
__global__ void edge_alpha(const int* __restrict__ src, const int* __restrict__ dst,
                           const float* __restrict__ eattr, const float* __restrict__ Kmat,
                           const float* __restrict__ kb, int l,
                           const float* __restrict__ as_, const float* __restrict__ ad_,
                           const int* __restrict__ perm, float* __restrict__ ew_s)
{
  int e = blockIdx.x * 256 + threadIdx.x;
  if (e >= Ee) return;
  const float4* p = (const float4*)(eattr + (size_t)e * EDIM);
  float ea[16];
  #pragma unroll
  for (int q = 0; q < 4; ++q) {
    float4 v = p[q];
    ea[q*4+0] = v.x; ea[q*4+1] = v.y; ea[q*4+2] = v.z; ea[q*4+3] = v.w;
  }
  float al[4];
  #pragma unroll
  for (int h = 0; h < 4; ++h) al[h] = kb[l*4 + h];
  #pragma unroll
  for (int k = 0; k < 16; ++k) {
    float v = ea[k];
    #pragma unroll
    for (int h = 0; h < 4; ++h) al[h] += v * Kmat[k*12 + l*4 + h];
  }
  int s = src[e], d = dst[e];
  float4 sv = *(const float4*)(as_ + (size_t)s * 4);
  float4 dv = *(const float4*)(ad_ + (size_t)d * 4);
  float4 a;
  a.x = al[0] + sv.x + dv.x; a.y = al[1] + sv.y + dv.y;
  a.z = al[2] + sv.z + dv.z; a.w = al[3] + sv.w + dv.w;
  a.x = (a.x > 0.f) ? a.x : SLOPE * a.x;
  a.y = (a.y > 0.f) ? a.y : SLOPE * a.y;
  a.z = (a.z > 0.f) ? a.z : SLOPE * a.z;
  a.w = (a.w > 0.f) ? a.w : SLOPE * a.w;
  float4 w;
  w.x = __expf(a.x); w.y = __expf(a.y); w.z = __expf(a.z); w.w = __expf(a.w);
  int pos = perm[e];
  *(float4*)(ew_s + (size_t)pos * 4) = w;
}

// CSR aggregation, unroll-4 for memory-level parallelism; softmax-normalize + bias fused
__global__ __launch_bounds__(256) void aggregate(const int* __restrict__ rowp, const int* __restrict__ src_s,
                                                 const float* __restrict__ ew_s, const float* __restrict__ xl,
                                                 const float* __restrict__ bias, float* __restrict__ outp)
{
  int n = blockIdx.x * 2 + (threadIdx.x >> 7);
  if (n >= Nn) return;
  int c = threadIdx.x & 127;
  int h = c >> 5;
  int beg = rowp[n], end = rowp[n+1];
  float acc = 0.f, wsum = 0.f;
  int i = beg;
  for (; i + 4 <= end; i += 4) {
    int s0 = src_s[i], s1 = src_s[i+1], s2 = src_s[i+2], s3 = src_s[i+3];
    float w0 = ew_s[(size_t)(i+0)*4 + h];
    float w1 = ew_s[(size_t)(i+1)*4 + h];
    float w2 = ew_s[(size_t)(i+2)*4 + h];
    float w3 = ew_s[(size_t)(i+3)*4 + h];
    float v0 = xl[(size_t)s0 * HC + c];
    float v1 = xl[(size_t)s1 * HC + c];
    float v2 = xl[(size_t)s2 * HC + c];
    float v3 = xl[(size_t)s3 * HC + c];
    acc += w0*v0 + w1*v1 + w2*v2 + w3*v3;
    wsum += w0 + w1 + w2 + w3;
  }
  for (; i < end; ++i) {
    int s = src_s[i];
    float w = ew_s[(size_t)i*4 + h];
    acc += w * xl[(size_t)s * HC + c];
    wsum += w;
  }
  outp[(size_t)n * HC + c] = acc / (wsum + 1e-16f) + bias[c];
}

__global__ void bn_reduce(const float* __restrict__ A, float* __restrict__ bnsum, float* __restrict__ bnsq)
{
  __shared__ float ss[256], sq[256];
  int t = threadIdx.x;
  int c = t & 127, hh = t >> 7;
  float s = 0.f, q = 0.f;
  for (int n = blockIdx.x * 2 + hh; n < Nn; n += gridDim.x * 2) {
    float v = A[(size_t)n * HC + c];
    s += v; q += v * v;
  }
  ss[t] = s; sq[t] = q;
  __syncthreads();
  if (t < 128) {
    atomicAdd(&bnsum[c], ss[t] + ss[t+128]);
    atomicAdd(&bnsq[c],  sq[t] + sq[t+128]);
  }
}

// global mean pool with BN+ReLU of final layer fused
__global__ void pool_kernel(const float* __restrict__ A, const int* __restrict__ batch,
                            const float* __restrict__ bnsum, const float* __restrict__ bnsq,
                            const float* __restrict__ gammaL, const float* __restrict__ betaL,
                            float* __restrict__ pool)
{
  int t = threadIdx.x;
  int c = t & 127, hh = t >> 7;
  float mu  = bnsum[c] * (1.f / Nn);
  float var = bnsq[c] * (1.f / Nn) - mu * mu;
  float s_ = rsqrtf(var + BN_EPS) * gammaL[c];
  float sh_ = betaL[c] - mu * s_;
  int n0 = blockIdx.x * 256;
  float accv = 0.f; int curg = -1;
  for (int i = hh; i < 256; i += 2) {
    int n = n0 + i;
    if (n >= Nn) break;
    int g = batch[n];
    if (g != curg) {
      if (curg >= 0) atomicAdd(&pool[(size_t)curg * HC + c], accv);
      curg = g; accv = 0.f;
    }
    accv += fmaxf(A[(size_t)n * HC + c] * s_ + sh_, 0.f);
  }
  if (curg >= 0) atomicAdd(&pool[(size_t)curg * HC + c], accv);
}

__global__ void cnt_kernel(const int* __restrict__ batch, int* __restrict__ cnt)
{
  int n = blockIdx.x * 256 + threadIdx.x;
  if (n < Nn) atomicAdd(&cnt[batch[n]], 1);
}

__global__ void final_fc(const float* __restrict__ pool, const int* __restrict__ cnt,
                         const float* __restrict__ fcW, const float* __restrict__ fcb,
                         float* __restrict__ out)
{
  int t = blockIdx.x * 256 + threadIdx.x;
  if (t >= Gg * NOUT) return;
  int g = t >> 1, o = t & 1;
  float cn = fmaxf((float)cnt[g], 1.f);
  float acc = 0.f;
  for (int k = 0; k < HC; ++k)
    acc += pool[(size_t)g * HC + k] * fcW[k * NOUT + o];
  out[t] = acc / cn + fcb[o];
}

extern "C" void kernel_launch(void* const* d_in, const int* in_sizes, int n_in,
                              void* d_out, int out_size, void* d_ws, size_t ws_size,
                              hipStream_t stream)
{
  const float* x      = (const float*)d_in[0];
  const int*   eidx   = (const int*)d_in[1];
  const float* eattr  = (const float*)d_in[2];
  const int*   batch  = (const int*)d_in[3];
  const float* efcW   = (const float*)d_in[4];
  const float* efcb   = (const float*)d_in[5];
  const float* Wall   = (const float*)d_in[6];
  const float* attS   = (const float*)d_in[7];
  const float* attD   = (const float*)d_in[8];
  const float* attE   = (const float*)d_in[9];
  const float* linE   = (const float*)d_in[10];
  const float* biases = (const float*)d_in[11];
  const float* gamma  = (const float*)d_in[12];
  const float* beta   = (const float*)d_in[13];
  const float* fcW    = (const float*)d_in[14];
  const float* fcb    = (const float*)d_in[15];
  float* out = (float*)d_out;

  const int* src = eidx;
  const int* dst = eidx + Ee;

  float* ws    = (float*)d_ws;
  float* bufA  = ws;                            // N*128
  float* bufB  = bufA + (size_t)Nn*HC;          // N*128
  float* as_   = bufB + (size_t)Nn*HC;          // N*4
  float* ad_   = as_ + (size_t)Nn*NHD;          // N*4
  float* ew_s  = ad_ + (size_t)Nn*NHD;          // E*4 (16B aligned)
  float* Kmat  = ew_s + (size_t)Ee*NHD;         // 192
  float* kb    = Kmat + 192;                    // 16
  float* bnsum = kb + 16;                       // 128
  float* bnsq  = bnsum + 128;                   // 128
  float* pool  = bnsq + 128;                    // G*128
  int*   cnt   = (int*)(pool + (size_t)Gg*HC);  // G
  int*   rowp  = cnt + Gg;                      // N+1
  int*   deg   = rowp + (Nn + 1);               // N
  int*   fill  = deg + Nn;                      // N  (deg..fill one memset)
  int*   src_s = fill + Nn;                     // E
  int*   perm  = src_s + Ee;                    // E
  int*   bsum  = perm + Ee;                     // NSB
  int*   bpre  = bsum + 128;                    // NSB

  compute_K<<<1, 512, 0, stream>>>(efcW, efcb, linE, attE, Kmat, kb);

  // CSR build (reused across all 3 layers)
  hipMemsetAsync(deg, 0, 2*Nn*sizeof(int), stream);
  k_hist<<<(Ee + 255)/256, 256, 0, stream>>>(dst, deg);
  k_bsum<<<NSB, 256, 0, stream>>>(deg, bsum);
  k_mid<<<1, 128, 0, stream>>>(bsum, bpre, rowp);
  k_scan<<<NSB, 256, 0, stream>>>(deg, bpre, rowp);
  k_fill<<<(Ee + 255)/256, 256, 0, stream>>>(src, dst, rowp, fill, src_s, perm);

  for (int l = 0; l < 3; ++l) {
    const float* Ain = (l == 0) ? x : bufA;
    // BN+ReLU of layer l-1 fused into A-load (bn stats from previous iteration)
    gemm_node<<<((Nn + 127)/128)*2, 256, 0, stream>>>(Ain, Wall + (size_t)l*HC*HC, bufB,
                                                      bnsum, bnsq, gamma + (l-1)*HC, beta + (l-1)*HC,
                                                      (l > 0) ? 1 : 0);
    node_attn<<<(Nn*NHD + 255)/256, 256, 0, stream>>>(bufB, attS + l*HC, attD + l*HC, as_, ad_);
    edge_alpha<<<(Ee + 255)/256, 256, 0, stream>>>(src, dst, eattr, Kmat, kb, l, as_, ad_, perm, ew_s);
    aggregate<<<(Nn + 1)/2, 256, 0, stream>>>(rowp, src_s, ew_s, bufB, biases + l*HC, bufA);
    hipMemsetAsync(bnsum, 0, 256*sizeof(float), stream);
    bn_reduce<<<256, 256, 0, stream>>>(bufA, bnsum, bnsq);
  }

  hipMemsetAsync(pool, 0, ((size_t)Gg*HC)*sizeof(float) + Gg*sizeof(int), stream);
  pool_kernel<<<(Nn + 255)/256, 256, 0, stream>>>(bufA, batch, bnsum, bnsq, gamma + 2*HC, beta + 2*HC, pool);
  cnt_kernel<<<(Nn + 255)/256, 256, 0, stream>>>(batch, cnt);
  final_fc<<<2, 256, 0, stream>>>(pool, cnt, fcW, fcb, out);
}

// Round 7
// 1152.910 us; speedup vs baseline: 2.1862x; 1.0857x over previous
//
#include <hip/hip_runtime.h>

#define Nn 100000
#define Ee 800000
#define HC 128
#define HID 32
#define NHD 4
#define EDIM 16
#define Gg 256
#define NOUT 2
#define SLOPE 0.2f
#define BN_EPS 1e-5f
#define SCHUNK 1024
#define NSB 98   // ceil(Nn/SCHUNK)

typedef unsigned int u32;

// ---- tiny weight precompute: Kmat[16][12], kb[12]  (edge-path algebraic fold) ----
__global__ void compute_K(const float* __restrict__ efcW, const float* __restrict__ efcb,
                          const float* __restrict__ linE, const float* __restrict__ attE,
                          float* __restrict__ Kmat, float* __restrict__ kb)
{
  __shared__ float Msh[384];   // M[l][j][h] = sum_c linE[l][j][h*32+c]*attE[l][h][c]
  int t = threadIdx.x;
  if (t < 384) {
    int l = t >> 7, j = (t >> 2) & 31, h = t & 3;
    float m = 0.f;
    for (int c = 0; c < 32; ++c)
      m += linE[(l*32 + j)*128 + h*32 + c] * attE[(l*4 + h)*32 + c];
    Msh[l*128 + j*4 + h] = m;
  }
  __syncthreads();
  if (t < 192) {
    int k = t / 12, col = t % 12, l = col >> 2, h = col & 3;
    float acc = 0.f;
    for (int j = 0; j < 32; ++j)
      acc += efcW[k*32 + j] * Msh[l*128 + j*4 + h];
    Kmat[k*12 + col] = acc;
  } else if (t < 204) {
    int col = t - 192, l = col >> 2, h = col & 3;
    float acc = 0.f;
    for (int j = 0; j < 32; ++j)
      acc += efcb[j] * Msh[l*128 + j*4 + h];
    kb[col] = acc;
  }
}

// ---- CSR build ----
__global__ void k_hist(const int* __restrict__ dst, int* __restrict__ deg)
{
  int e = blockIdx.x * 256 + threadIdx.x;
  if (e < Ee) atomicAdd(&deg[dst[e]], 1);
}

__global__ void k_bsum(const int* __restrict__ deg, int* __restrict__ bsum)
{
  __shared__ int sh[256];
  int b = blockIdx.x, t = threadIdx.x;
  int s = 0;
  for (int i = t; i < SCHUNK; i += 256) {
    int idx = b*SCHUNK + i;
    if (idx < Nn) s += deg[idx];
  }
  sh[t] = s; __syncthreads();
  for (int o = 128; o; o >>= 1) { if (t < o) sh[t] += sh[t+o]; __syncthreads(); }
  if (!t) bsum[b] = sh[0];
}

__global__ void k_mid(const int* __restrict__ bsum, int* __restrict__ bpre, int* __restrict__ rowp)
{
  __shared__ int sh[NSB];
  int t = threadIdx.x;
  if (t < NSB) sh[t] = bsum[t];
  __syncthreads();
  if (!t) {
    int run = 0;
    for (int i = 0; i < NSB; ++i) { int v = sh[i]; sh[i] = run; run += v; }
    rowp[Nn] = run;
  }
  __syncthreads();
  if (t < NSB) bpre[t] = sh[t];
}

__global__ void k_scan(const int* __restrict__ deg, const int* __restrict__ bpre, int* __restrict__ rowp)
{
  __shared__ int sh[SCHUNK];
  int b = blockIdx.x, t = threadIdx.x;
  for (int i = t; i < SCHUNK; i += 256) {
    int idx = b*SCHUNK + i;
    sh[i] = (idx < Nn) ? deg[idx] : 0;
  }
  __syncthreads();
  if (!t) {
    int run = 0;
    for (int i = 0; i < SCHUNK; ++i) { int v = sh[i]; sh[i] = run; run += v; }
  }
  __syncthreads();
  int base = bpre[b];
  for (int i = t; i < SCHUNK; i += 256) {
    int idx = b*SCHUNK + i;
    if (idx < Nn) rowp[idx] = sh[i] + base;
  }
}

__global__ void k_fill(const int* __restrict__ src, const int* __restrict__ dst,
                       const int* __restrict__ rowp, int* __restrict__ fill,
                       int* __restrict__ src_s, int* __restrict__ perm)
{
  int e = blockIdx.x * 256 + threadIdx.x;
  if (e >= Ee) return;
  int d = dst[e];
  int pos = rowp[d] + atomicAdd(&fill[d], 1);
  src_s[pos] = src[e];
  perm[e] = pos;
}

// ---- GEMM: C[N,128] = BN?(A[N,128]) @ W[128,128]
__global__ __launch_bounds__(256) void gemm_node(const float* __restrict__ A,
                                                 const float* __restrict__ W,
                                                 float* __restrict__ C,
                                                 const float* __restrict__ bnsum,
                                                 const float* __restrict__ bnsq,
                                                 const float* __restrict__ gammaL,
                                                 const float* __restrict__ betaL,
                                                 int apply_bn)
{
  __shared__ float Wh[HC][68];   // 128 k x 64 cols staged, stride 68
  __shared__ float sc_[HC], sh_[HC];
  int t = threadIdx.x;
  int hf = blockIdx.x & 1;
  int row0 = (blockIdx.x >> 1) * 128;
  for (int i = t; i < HC*16; i += 256) {
    int k = i >> 4, c4 = i & 15;
    *(float4*)&Wh[k][c4*4] = *(const float4*)(W + (size_t)k*HC + hf*64 + c4*4);
  }
  if (t < HC) {
    if (apply_bn) {
      float mu  = bnsum[t] * (1.f / Nn);
      float var = bnsq[t] * (1.f / Nn) - mu * mu;
      float s = rsqrtf(var + BN_EPS) * gammaL[t];
      sc_[t] = s;
      sh_[t] = betaL[t] - mu * s;
    } else { sc_[t] = 1.f; sh_[t] = 0.f; }
  }
  __syncthreads();
  int cg = t & 7, r = t >> 3;   // cols hf*64 + cg*8 .. +7 ; rows r+32i
  int rows[4];
  #pragma unroll
  for (int i = 0; i < 4; ++i) {
    int rr = row0 + r + 32*i;
    rows[i] = (rr < Nn) ? rr : (Nn - 1);
  }
  float4 acc[4][2];
  #pragma unroll
  for (int i = 0; i < 4; ++i) {
    acc[i][0] = make_float4(0.f,0.f,0.f,0.f);
    acc[i][1] = make_float4(0.f,0.f,0.f,0.f);
  }
  if (apply_bn) {
    for (int k4 = 0; k4 < 32; ++k4) {
      float4 s4 = *(const float4*)&sc_[k4*4];
      float4 h4 = *(const float4*)&sh_[k4*4];
      float4 a[4];
      #pragma unroll
      for (int i = 0; i < 4; ++i) {
        float4 v = *(const float4*)(A + (size_t)rows[i]*HC + k4*4);
        v.x = fmaxf(v.x*s4.x + h4.x, 0.f);
        v.y = fmaxf(v.y*s4.y + h4.y, 0.f);
        v.z = fmaxf(v.z*s4.z + h4.z, 0.f);
        v.w = fmaxf(v.w*s4.w + h4.w, 0.f);
        a[i] = v;
      }
      float4 w0[4], w1[4];
      #pragma unroll
      for (int j = 0; j < 4; ++j) {
        w0[j] = *(const float4*)&Wh[k4*4 + j][cg*8];
        w1[j] = *(const float4*)&Wh[k4*4 + j][cg*8 + 4];
      }
      #pragma unroll
      for (int i = 0; i < 4; ++i) {
        float4 av = a[i];
        acc[i][0].x += av.x*w0[0].x + av.y*w0[1].x + av.z*w0[2].x + av.w*w0[3].x;
        acc[i][0].y += av.x*w0[0].y + av.y*w0[1].y + av.z*w0[2].y + av.w*w0[3].y;
        acc[i][0].z += av.x*w0[0].z + av.y*w0[1].z + av.z*w0[2].z + av.w*w0[3].z;
        acc[i][0].w += av.x*w0[0].w + av.y*w0[1].w + av.z*w0[2].w + av.w*w0[3].w;
        acc[i][1].x += av.x*w1[0].x + av.y*w1[1].x + av.z*w1[2].x + av.w*w1[3].x;
        acc[i][1].y += av.x*w1[0].y + av.y*w1[1].y + av.z*w1[2].y + av.w*w1[3].y;
        acc[i][1].z += av.x*w1[0].z + av.y*w1[1].z + av.z*w1[2].z + av.w*w1[3].z;
        acc[i][1].w += av.x*w1[0].w + av.y*w1[1].w + av.z*w1[2].w + av.w*w1[3].w;
      }
    }
  } else {
    for (int k4 = 0; k4 < 32; ++k4) {
      float4 a[4];
      #pragma unroll
      for (int i = 0; i < 4; ++i)
        a[i] = *(const float4*)(A + (size_t)rows[i]*HC + k4*4);
      float4 w0[4], w1[4];
      #pragma unroll
      for (int j = 0; j < 4; ++j) {
        w0[j] = *(const float4*)&Wh[k4*4 + j][cg*8];
        w1[j] = *(const float4*)&Wh[k4*4 + j][cg*8 + 4];
      }
      #pragma unroll
      for (int i = 0; i < 4; ++i) {
        float4 av = a[i];
        acc[i][0].x += av.x*w0[0].x + av.y*w0[1].x + av.z*w0[2].x + av.w*w0[3].x;
        acc[i][0].y += av.x*w0[0].y + av.y*w0[1].y + av.z*w0[2].y + av.w*w0[3].y;
        acc[i][0].z += av.x*w0[0].z + av.y*w0[1].z + av.z*w0[2].z + av.w*w0[3].z;
        acc[i][0].w += av.x*w0[0].w + av.y*w0[1].w + av.z*w0[2].w + av.w*w0[3].w;
        acc[i][1].x += av.x*w1[0].x + av.y*w1[1].x + av.z*w1[2].x + av.w*w1[3].x;
        acc[i][1].y += av.x*w1[0].y + av.y*w1[1].y + av.z*w1[2].y + av.w*w1[3].y;
        acc[i][1].z += av.x*w1[0].z + av.y*w1[1].z + av.z*w1[2].z + av.w*w1[3].z;
        acc[i][1].w += av.x*w1[0].w + av.y*w1[1].w + av.z*w1[2].w + av.w*w1[3].w;
      }
    }
  }
  #pragma unroll
  for (int i = 0; i < 4; ++i) {
    int row = row0 + r + 32*i;
    if (row < Nn) {
      *(float4*)(C + (size_t)row*HC + hf*64 + cg*8)     = acc[i][0];
      *(float4*)(C + (size_t)row*HC + hf*64 + cg*8 + 4) = acc[i][1];
    }
  }
}

__global__ void node_attn(const float* __restrict__ xl, const float* __restrict__ aS,
                          const float* __restrict__ aD,
                          float* __restrict__ as_, float* __restrict__ ad_)
{
  int t = blockIdx.x * 256 + threadIdx.x;
  if (t >= Nn*NHD) return;
  int n = t >> 2, h = t & 3;
  const float4* xr = (const float4*)(xl + (size_t)n * HC + h * HID);
  float s1 = 0.f, s2 = 0.f;
  #pragma unroll
  for (int j = 0; j < 8; ++j) {
    float4 v = xr[j];
    float4 s = *(const float4*)(aS + h * HID + j * 4);
    float4 d = *(const float4*)(aD + h * HID + j * 4);
    s1 += v.x*s.x + v.y*s.y + v.z*s.z + v.w*s.w;
    s2 += v.x*d.x + v.y*d.y + v.z*d.z + v.w*d.w;
  }
  as_[t] = s1; ad_[t] = s2;
}

// alpha -> leaky -> w=exp(alpha), scattered into dst-sorted position
__global__ void edge_alpha(const int* __restrict__ src, const int* __restrict__ dst,
                           const float* __restrict__ eattr, const float* __restrict__ Kmat,
                           const float* __restrict__ kb, int l,
                           const float* __restrict__ as_, const float* __restrict__ ad_,
                           const int* __restrict__ perm, float* __restrict__ ew_s)
{
  int e = blockIdx.x * 256 + threadIdx.x;
  if (e >= Ee) return;
  const float4* p = (const float4*)(eattr + (size_t)e * EDIM);
  float ea[16];
  #pragma unroll
  for (int q = 0; q < 4; ++q) {
    float4 v = p[q];
    ea[q*4+0] = v.x; ea[q*4+1] = v.y; ea[q*4+2] = v.z; ea[q*4+3] = v.w;
  }
  float al[4];
  #pragma unroll
  for (int h = 0; h < 4; ++h) al[h] = kb[l*4 + h];
  #pragma unroll
  for (int k = 0; k < 16; ++k) {
    float v = ea[k];
    #pragma unroll
    for (int h = 0; h < 4; ++h) al[h] += v * Kmat[k*12 + l*4 + h];
  }
  int s = src[e], d = dst[e];
  float4 sv = *(const float4*)(as_ + (size_t)s * 4);
  float4 dv = *(const float4*)(ad_ + (size_t)d * 4);
  float4 a;
  a.x = al[0] + sv.x + dv.x; a.y = al[1] + sv.y + dv.y;
  a.z = al[2] + sv.z + dv.z; a.w = al[3] + sv.w + dv.w;
  a.x = (a.x > 0.f) ? a.x : SLOPE * a.x;
  a.y = (a.y > 0.f) ? a.y : SLOPE * a.y;
  a.z = (a.z > 0.f) ? a.z : SLOPE * a.z;
  a.w = (a.w > 0.f) ? a.w : SLOPE * a.w;
  float4 w;
  w.x = __expf(a.x); w.y = __expf(a.y); w.z = __expf(a.z); w.w = __expf(a.w);
  int pos = perm[e];
  *(float4*)(ew_s + (size_t)pos * 4) = w;
}

// CSR aggregation, unroll-8 for memory-level parallelism; softmax-normalize + bias fused
__global__ __launch_bounds__(256) void aggregate(const int* __restrict__ rowp, const int* __restrict__ src_s,
                                                 const float* __restrict__ ew_s, const float* __restrict__ xl,
                                                 const float* __restrict__ bias, float* __restrict__ outp)
{
  int n = blockIdx.x * 2 + (threadIdx.x >> 7);
  if (n >= Nn) return;
  int c = threadIdx.x & 127;
  int h = c >> 5;
  int beg = rowp[n], end = rowp[n+1];
  float acc = 0.f, wsum = 0.f;
  int i = beg;
  for (; i + 8 <= end; i += 8) {
    int   s[8]; float w[8], v[8];
    #pragma unroll
    for (int j = 0; j < 8; ++j) s[j] = src_s[i+j];
    #pragma unroll
    for (int j = 0; j < 8; ++j) w[j] = ew_s[(size_t)(i+j)*4 + h];
    #pragma unroll
    for (int j = 0; j < 8; ++j) v[j] = xl[(size_t)s[j] * HC + c];
    #pragma unroll
    for (int j = 0; j < 8; ++j) { acc += w[j]*v[j]; wsum += w[j]; }
  }
  for (; i < end; ++i) {
    int s = src_s[i];
    float w = ew_s[(size_t)i*4 + h];
    acc += w * xl[(size_t)s * HC + c];
    wsum += w;
  }
  outp[(size_t)n * HC + c] = acc / (wsum + 1e-16f) + bias[c];
}

__global__ void bn_reduce(const float* __restrict__ A, float* __restrict__ bnsum, float* __restrict__ bnsq)
{
  __shared__ float ss[256], sq[256];
  int t = threadIdx.x;
  int c = t & 127, hh = t >> 7;
  float s = 0.f, q = 0.f;
  for (int n = blockIdx.x * 2 + hh; n < Nn; n += gridDim.x * 2) {
    float v = A[(size_t)n * HC + c];
    s += v; q += v * v;
  }
  ss[t] = s; sq[t] = q;
  __syncthreads();
  if (t < 128) {
    atomicAdd(&bnsum[c], ss[t] + ss[t+128]);
    atomicAdd(&bnsq[c],  sq[t] + sq[t+128]);
  }
}

// global mean pool with BN+ReLU of final layer fused
__global__ void pool_kernel(const float* __restrict__ A, const int* __restrict__ batch,
                            const float* __restrict__ bnsum, const float* __restrict__ bnsq,
                            const float* __restrict__ gammaL, const float* __restrict__ betaL,
                            float* __restrict__ pool)
{
  int t = threadIdx.x;
  int c = t & 127, hh = t >> 7;
  float mu  = bnsum[c] * (1.f / Nn);
  float var = bnsq[c] * (1.f / Nn) - mu * mu;
  float s_ = rsqrtf(var + BN_EPS) * gammaL[c];
  float sh_ = betaL[c] - mu * s_;
  int n0 = blockIdx.x * 256;
  float accv = 0.f; int curg = -1;
  for (int i = hh; i < 256; i += 2) {
    int n = n0 + i;
    if (n >= Nn) break;
    int g = batch[n];
    if (g != curg) {
      if (curg >= 0) atomicAdd(&pool[(size_t)curg * HC + c], accv);
      curg = g; accv = 0.f;
    }
    accv += fmaxf(A[(size_t)n * HC + c] * s_ + sh_, 0.f);
  }
  if (curg >= 0) atomicAdd(&pool[(size_t)curg * HC + c], accv);
}

// batch is sorted: cnt[g] = lower_bound(g+1) - lower_bound(g); fused into FC
__device__ __forceinline__ int lbound(const int* __restrict__ a, int n, int key)
{
  int lo = 0, hi = n;
  while (lo < hi) {
    int mid = (lo + hi) >> 1;
    if (a[mid] < key) lo = mid + 1; else hi = mid;
  }
  return lo;
}

__global__ void final_fc(const float* __restrict__ pool, const int* __restrict__ batch,
                         const float* __restrict__ fcW, const float* __restrict__ fcb,
                         float* __restrict__ out)
{
  int t = blockIdx.x * 256 + threadIdx.x;
  if (t >= Gg * NOUT) return;
  int g = t >> 1, o = t & 1;
  int lo = lbound(batch, Nn, g);
  int hi = lbound(batch, Nn, g + 1);
  float cn = fmaxf((float)(hi - lo), 1.f);
  float acc = 0.f;
  for (int k = 0; k < HC; ++k)
    acc += pool[(size_t)g * HC + k] * fcW[k * NOUT + o];
  out[t] = acc / cn + fcb[o];
}

extern "C" void kernel_launch(void* const* d_in, const int* in_sizes, int n_in,
                              void* d_out, int out_size, void* d_ws, size_t ws_size,
                              hipStream_t stream)
{
  const float* x      = (const float*)d_in[0];
  const int*   eidx   = (const int*)d_in[1];
  const float* eattr  = (const float*)d_in[2];
  const int*   batch  = (const int*)d_in[3];
  const float* efcW   = (const float*)d_in[4];
  const float* efcb   = (const float*)d_in[5];
  const float* Wall   = (const float*)d_in[6];
  const float* attS   = (const float*)d_in[7];
  const float* attD   = (const float*)d_in[8];
  const float* attE   = (const float*)d_in[9];
  const float* linE   = (const float*)d_in[10];
  const float* biases = (const float*)d_in[11];
  const float* gamma  = (const float*)d_in[12];
  const float* beta   = (const float*)d_in[13];
  const float* fcW    = (const float*)d_in[14];
  const float* fcb    = (const float*)d_in[15];
  float* out = (float*)d_out;

  const int* src = eidx;
  const int* dst = eidx + Ee;

  float* ws    = (float*)d_ws;
  float* bufA  = ws;                            // N*128
  float* bufB  = bufA + (size_t)Nn*HC;          // N*128
  float* as_   = bufB + (size_t)Nn*HC;          // N*4
  float* ad_   = as_ + (size_t)Nn*NHD;          // N*4
  float* ew_s  = ad_ + (size_t)Nn*NHD;          // E*4 (16B aligned)
  float* Kmat  = ew_s + (size_t)Ee*NHD;         // 192
  float* kb    = Kmat + 192;                    // 16
  float* bnsum = kb + 16;                       // 128
  float* bnsq  = bnsum + 128;                   // 128
  float* pool  = bnsq + 128;                    // G*128
  int*   rowp  = (int*)(pool + (size_t)Gg*HC);  // N+1
  int*   deg   = rowp + (Nn + 1);               // N
  int*   fill  = deg + Nn;                      // N  (deg..fill one memset)
  int*   src_s = fill + Nn;                     // E
  int*   perm  = src_s + Ee;                    // E
  int*   bsum  = perm + Ee;                     // NSB
  int*   bpre  = bsum + 128;                    // NSB

  compute_K<<<1, 512, 0, stream>>>(efcW, efcb, linE, attE, Kmat, kb);

  // CSR build (reused across all 3 layers)
  hipMemsetAsync(deg, 0, 2*Nn*sizeof(int), stream);
  k_hist<<<(Ee + 255)/256, 256, 0, stream>>>(dst, deg);
  k_bsum<<<NSB, 256, 0, stream>>>(deg, bsum);
  k_mid<<<1, 128, 0, stream>>>(bsum, bpre, rowp);
  k_scan<<<NSB, 256, 0, stream>>>(deg, bpre, rowp);
  k_fill<<<(Ee + 255)/256, 256, 0, stream>>>(src, dst, rowp, fill, src_s, perm);

  for (int l = 0; l < 3; ++l) {
    const float* Ain = (l == 0) ? x : bufA;
    gemm_node<<<((Nn + 127)/128)*2, 256, 0, stream>>>(Ain, Wall + (size_t)l*HC*HC, bufB,
                                                      bnsum, bnsq, gamma + (l-1)*HC, beta + (l-1)*HC,
                                                      (l > 0) ? 1 : 0);
    node_attn<<<(Nn*NHD + 255)/256, 256, 0, stream>>>(bufB, attS + l*HC, attD + l*HC, as_, ad_);
    edge_alpha<<<(Ee + 255)/256, 256, 0, stream>>>(src, dst, eattr, Kmat, kb, l, as_, ad_, perm, ew_s);
    aggregate<<<(Nn + 1)/2, 256, 0, stream>>>(rowp, src_s, ew_s, bufB, biases + l*HC, bufA);
    hipMemsetAsync(bnsum, 0, 256*sizeof(float), stream);
    bn_reduce<<<256, 256, 0, stream>>>(bufA, bnsum, bnsq);
  }

  hipMemsetAsync(pool, 0, (size_t)Gg*HC*sizeof(float), stream);
  pool_kernel<<<(Nn + 255)/256, 256, 0, stream>>>(bufA, batch, bnsum, bnsq, gamma + 2*HC, beta + 2*HC, pool);
  final_fc<<<2, 256, 0, stream>>>(pool, batch, fcW, fcb, out);
}

// Round 8
// 966.812 us; speedup vs baseline: 2.6070x; 1.1925x over previous
//
#include <hip/hip_runtime.h>

#define Nn 100000
#define Ee 800000
#define HC 128
#define HID 32
#define NHD 4
#define EDIM 16
#define Gg 256
#define NOUT 2
#define SLOPE 0.2f
#define BN_EPS 1e-5f
#define SCHUNK 1024
#define NSB 98   // ceil(Nn/SCHUNK)

typedef unsigned int u32;

// ---- tiny weight precompute: Kmat[16][12], kb[12]  (edge-path algebraic fold) ----
__global__ void compute_K(const float* __restrict__ efcW, const float* __restrict__ efcb,
                          const float* __restrict__ linE, const float* __restrict__ attE,
                          float* __restrict__ Kmat, float* __restrict__ kb)
{
  __shared__ float Msh[384];   // M[l][j][h] = sum_c linE[l][j][h*32+c]*attE[l][h][c]
  int t = threadIdx.x;
  if (t < 384) {
    int l = t >> 7, j = (t >> 2) & 31, h = t & 3;
    float m = 0.f;
    for (int c = 0; c < 32; ++c)
      m += linE[(l*32 + j)*128 + h*32 + c] * attE[(l*4 + h)*32 + c];
    Msh[l*128 + j*4 + h] = m;
  }
  __syncthreads();
  if (t < 192) {
    int k = t / 12, col = t % 12, l = col >> 2, h = col & 3;
    float acc = 0.f;
    for (int j = 0; j < 32; ++j)
      acc += efcW[k*32 + j] * Msh[l*128 + j*4 + h];
    Kmat[k*12 + col] = acc;
  } else if (t < 204) {
    int col = t - 192, l = col >> 2, h = col & 3;
    float acc = 0.f;
    for (int j = 0; j < 32; ++j)
      acc += efcb[j] * Msh[l*128 + j*4 + h];
    kb[col] = acc;
  }
}

// ---- CSR build ----
__global__ void k_hist(const int* __restrict__ dst, int* __restrict__ deg)
{
  int e = blockIdx.x * 256 + threadIdx.x;
  if (e < Ee) atomicAdd(&deg[dst[e]], 1);
}

__global__ void k_bsum(const int* __restrict__ deg, int* __restrict__ bsum)
{
  __shared__ int sh[256];
  int b = blockIdx.x, t = threadIdx.x;
  int s = 0;
  for (int i = t; i < SCHUNK; i += 256) {
    int idx = b*SCHUNK + i;
    if (idx < Nn) s += deg[idx];
  }
  sh[t] = s; __syncthreads();
  for (int o = 128; o; o >>= 1) { if (t < o) sh[t] += sh[t+o]; __syncthreads(); }
  if (!t) bsum[b] = sh[0];
}

__global__ void k_mid(const int* __restrict__ bsum, int* __restrict__ bpre, int* __restrict__ rowp)
{
  __shared__ int sh[NSB];
  int t = threadIdx.x;
  if (t < NSB) sh[t] = bsum[t];
  __syncthreads();
  if (!t) {
    int run = 0;
    for (int i = 0; i < NSB; ++i) { int v = sh[i]; sh[i] = run; run += v; }
    rowp[Nn] = run;
  }
  __syncthreads();
  if (t < NSB) bpre[t] = sh[t];
}

__global__ void k_scan(const int* __restrict__ deg, const int* __restrict__ bpre, int* __restrict__ rowp)
{
  __shared__ int sh[SCHUNK];
  int b = blockIdx.x, t = threadIdx.x;
  for (int i = t; i < SCHUNK; i += 256) {
    int idx = b*SCHUNK + i;
    sh[i] = (idx < Nn) ? deg[idx] : 0;
  }
  __syncthreads();
  if (!t) {
    int run = 0;
    for (int i = 0; i < SCHUNK; ++i) { int v = sh[i]; sh[i] = run; run += v; }
  }
  __syncthreads();
  int base = bpre[b];
  for (int i = t; i < SCHUNK; i += 256) {
    int idx = b*SCHUNK + i;
    if (idx < Nn) rowp[idx] = sh[i] + base;
  }
}

__global__ void k_fill(const int* __restrict__ src, const int* __restrict__ dst,
                       const int* __restrict__ rowp, int* __restrict__ fill,
                       int* __restrict__ src_s, int* __restrict__ perm)
{
  int e = blockIdx.x * 256 + threadIdx.x;
  if (e >= Ee) return;
  int d = dst[e];
  int pos = rowp[d] + atomicAdd(&fill[d], 1);
  src_s[pos] = src[e];
  perm[e] = pos;
}

// ---- GEMM: C[N,128] = BN?(A[N,128]) @ W[128,128], node_attn dots fused in epilogue
__global__ __launch_bounds__(256) void gemm_node(const float* __restrict__ A,
                                                 const float* __restrict__ W,
                                                 float* __restrict__ C,
                                                 const float* __restrict__ bnsum,
                                                 const float* __restrict__ bnsq,
                                                 const float* __restrict__ gammaL,
                                                 const float* __restrict__ betaL,
                                                 int apply_bn,
                                                 const float* __restrict__ aS,
                                                 const float* __restrict__ aD,
                                                 float* __restrict__ as_,
                                                 float* __restrict__ ad_)
{
  __shared__ float Wh[HC][68];   // 128 k x 64 cols staged, stride 68
  __shared__ float sc_[HC], sh_[HC];
  int t = threadIdx.x;
  int hf = blockIdx.x & 1;
  int row0 = (blockIdx.x >> 1) * 128;
  for (int i = t; i < HC*16; i += 256) {
    int k = i >> 4, c4 = i & 15;
    *(float4*)&Wh[k][c4*4] = *(const float4*)(W + (size_t)k*HC + hf*64 + c4*4);
  }
  if (t < HC) {
    if (apply_bn) {
      float mu  = bnsum[t] * (1.f / Nn);
      float var = bnsq[t] * (1.f / Nn) - mu * mu;
      float s = rsqrtf(var + BN_EPS) * gammaL[t];
      sc_[t] = s;
      sh_[t] = betaL[t] - mu * s;
    } else { sc_[t] = 1.f; sh_[t] = 0.f; }
  }
  __syncthreads();
  int cg = t & 7, r = t >> 3;   // cols hf*64 + cg*8 .. +7 ; rows r+32i
  int rows[4];
  #pragma unroll
  for (int i = 0; i < 4; ++i) {
    int rr = row0 + r + 32*i;
    rows[i] = (rr < Nn) ? rr : (Nn - 1);
  }
  float4 acc[4][2];
  #pragma unroll
  for (int i = 0; i < 4; ++i) {
    acc[i][0] = make_float4(0.f,0.f,0.f,0.f);
    acc[i][1] = make_float4(0.f,0.f,0.f,0.f);
  }
  if (apply_bn) {
    for (int k4 = 0; k4 < 32; ++k4) {
      float4 s4 = *(const float4*)&sc_[k4*4];
      float4 h4 = *(const float4*)&sh_[k4*4];
      float4 a[4];
      #pragma unroll
      for (int i = 0; i < 4; ++i) {
        float4 v = *(const float4*)(A + (size_t)rows[i]*HC + k4*4);
        v.x = fmaxf(v.x*s4.x + h4.x, 0.f);
        v.y = fmaxf(v.y*s4.y + h4.y, 0.f);
        v.z = fmaxf(v.z*s4.z + h4.z, 0.f);
        v.w = fmaxf(v.w*s4.w + h4.w, 0.f);
        a[i] = v;
      }
      float4 w0[4], w1[4];
      #pragma unroll
      for (int j = 0; j < 4; ++j) {
        w0[j] = *(const float4*)&Wh[k4*4 + j][cg*8];
        w1[j] = *(const float4*)&Wh[k4*4 + j][cg*8 + 4];
      }
      #pragma unroll
      for (int i = 0; i < 4; ++i) {
        float4 av = a[i];
        acc[i][0].x += av.x*w0[0].x + av.y*w0[1].x + av.z*w0[2].x + av.w*w0[3].x;
        acc[i][0].y += av.x*w0[0].y + av.y*w0[1].y + av.z*w0[2].y + av.w*w0[3].y;
        acc[i][0].z += av.x*w0[0].z + av.y*w0[1].z + av.z*w0[2].z + av.w*w0[3].z;
        acc[i][0].w += av.x*w0[0].w + av.y*w0[1].w + av.z*w0[2].w + av.w*w0[3].w;
        acc[i][1].x += av.x*w1[0].x + av.y*w1[1].x + av.z*w1[2].x + av.w*w1[3].x;
        acc[i][1].y += av.x*w1[0].y + av.y*w1[1].y + av.z*w1[2].y + av.w*w1[3].y;
        acc[i][1].z += av.x*w1[0].z + av.y*w1[1].z + av.z*w1[2].z + av.w*w1[3].z;
        acc[i][1].w += av.x*w1[0].w + av.y*w1[1].w + av.z*w1[2].w + av.w*w1[3].w;
      }
    }
  } else {
    for (int k4 = 0; k4 < 32; ++k4) {
      float4 a[4];
      #pragma unroll
      for (int i = 0; i < 4; ++i)
        a[i] = *(const float4*)(A + (size_t)rows[i]*HC + k4*4);
      float4 w0[4], w1[4];
      #pragma unroll
      for (int j = 0; j < 4; ++j) {
        w0[j] = *(const float4*)&Wh[k4*4 + j][cg*8];
        w1[j] = *(const float4*)&Wh[k4*4 + j][cg*8 + 4];
      }
      #pragma unroll
      for (int i = 0; i < 4; ++i) {
        float4 av = a[i];
        acc[i][0].x += av.x*w0[0].x + av.y*w0[1].x + av.z*w0[2].x + av.w*w0[3].x;
        acc[i][0].y += av.x*w0[0].y + av.y*w0[1].y + av.z*w0[2].y + av.w*w0[3].y;
        acc[i][0].z += av.x*w0[0].z + av.y*w0[1].z + av.z*w0[2].z + av.w*w0[3].z;
        acc[i][0].w += av.x*w0[0].w + av.y*w0[1].w + av.z*w0[2].w + av.w*w0[3].w;
        acc[i][1].x += av.x*w1[0].x + av.y*w1[1].x + av.z*w1[2].x + av.w*w1[3].x;
        acc[i][1].y += av.x*w1[0].y + av.y*w1[1].y + av.z*w1[2].y + av.w*w1[3].y;
        acc[i][1].z += av.x*w1[0].z + av.y*w1[1].z + av.z*w1[2].z + av.w*w1[3].z;
        acc[i][1].w += av.x*w1[0].w + av.y*w1[1].w + av.z*w1[2].w + av.w*w1[3].w;
      }
    }
  }
  #pragma unroll
  for (int i = 0; i < 4; ++i) {
    int row = row0 + r + 32*i;
    if (row < Nn) {
      *(float4*)(C + (size_t)row*HC + hf*64 + cg*8)     = acc[i][0];
      *(float4*)(C + (size_t)row*HC + hf*64 + cg*8 + 4) = acc[i][1];
    }
  }
  // fused node_attn: this col-half covers heads hf*2 + (cg>>2); 8-col group is within one head
  float4 aS0 = *(const float4*)(aS + hf*64 + cg*8);
  float4 aS1 = *(const float4*)(aS + hf*64 + cg*8 + 4);
  float4 aD0 = *(const float4*)(aD + hf*64 + cg*8);
  float4 aD1 = *(const float4*)(aD + hf*64 + cg*8 + 4);
  #pragma unroll
  for (int i = 0; i < 4; ++i) {
    float s1 = acc[i][0].x*aS0.x + acc[i][0].y*aS0.y + acc[i][0].z*aS0.z + acc[i][0].w*aS0.w
             + acc[i][1].x*aS1.x + acc[i][1].y*aS1.y + acc[i][1].z*aS1.z + acc[i][1].w*aS1.w;
    float s2 = acc[i][0].x*aD0.x + acc[i][0].y*aD0.y + acc[i][0].z*aD0.z + acc[i][0].w*aD0.w
             + acc[i][1].x*aD1.x + acc[i][1].y*aD1.y + acc[i][1].z*aD1.z + acc[i][1].w*aD1.w;
    s1 += __shfl_xor(s1, 1); s1 += __shfl_xor(s1, 2);
    s2 += __shfl_xor(s2, 1); s2 += __shfl_xor(s2, 2);
    if ((cg & 3) == 0) {
      int row = row0 + r + 32*i;
      if (row < Nn) {
        int h = hf*2 + (cg >> 2);
        as_[row*NHD + h] = s1;
        ad_[row*NHD + h] = s2;
      }
    }
  }
}

// alpha -> leaky -> w=exp(alpha), scattered into dst-sorted position
__global__ void edge_alpha(const int* __restrict__ src, const int* __restrict__ dst,
                           const float* __restrict__ eattr, const float* __restrict__ Kmat,
                           const float* __restrict__ kb, int l,
                           const float* __restrict__ as_, const float* __restrict__ ad_,
                           const int* __restrict__ perm, float* __restrict__ ew_s)
{
  int e = blockIdx.x * 256 + threadIdx.x;
  if (e >= Ee) return;
  const float4* p = (const float4*)(eattr + (size_t)e * EDIM);
  float ea[16];
  #pragma unroll
  for (int q = 0; q < 4; ++q) {
    float4 v = p[q];
    ea[q*4+0] = v.x; ea[q*4+1] = v.y; ea[q*4+2] = v.z; ea[q*4+3] = v.w;
  }
  float al[4];
  #pragma unroll
  for (int h = 0; h < 4; ++h) al[h] = kb[l*4 + h];
  #pragma unroll
  for (int k = 0; k < 16; ++k) {
    float v = ea[k];
    #pragma unroll
    for (int h = 0; h < 4; ++h) al[h] += v * Kmat[k*12 + l*4 + h];
  }
  int s = src[e], d = dst[e];
  float4 sv = *(const float4*)(as_ + (size_t)s * 4);
  float4 dv = *(const float4*)(ad_ + (size_t)d * 4);
  float4 a;
  a.x = al[0] + sv.x + dv.x; a.y = al[1] + sv.y + dv.y;
  a.z = al[2] + sv.z + dv.z; a.w = al[3] + sv.w + dv.w;
  a.x = (a.x > 0.f) ? a.x : SLOPE * a.x;
  a.y = (a.y > 0.f) ? a.y : SLOPE * a.y;
  a.z = (a.z > 0.f) ? a.z : SLOPE * a.z;
  a.w = (a.w > 0.f) ? a.w : SLOPE * a.w;
  float4 w;
  w.x = __expf(a.x); w.y = __expf(a.y); w.z = __expf(a.z); w.w = __expf(a.w);
  int pos = perm[e];
  *(float4*)(ew_s + (size_t)pos * 4) = w;
}

// CSR aggregation: 32 thr/node (float4 per thread), 8 nodes/block, unroll-4 edges
__global__ __launch_bounds__(256) void aggregate(const int* __restrict__ rowp, const int* __restrict__ src_s,
                                                 const float* __restrict__ ew_s, const float* __restrict__ xl,
                                                 const float* __restrict__ bias, float* __restrict__ outp)
{
  int n = blockIdx.x * 8 + (threadIdx.x >> 5);
  if (n >= Nn) return;
  int c4 = threadIdx.x & 31;        // channels c4*4 .. c4*4+3 (single head: h = c4>>3)
  int h = c4 >> 3;
  int beg = rowp[n], end = rowp[n+1];
  float4 acc = make_float4(0.f,0.f,0.f,0.f);
  float wsum = 0.f;
  int i = beg;
  for (; i + 4 <= end; i += 4) {
    int s0 = src_s[i], s1 = src_s[i+1], s2 = src_s[i+2], s3 = src_s[i+3];
    float w0 = ew_s[(size_t)(i+0)*4 + h];
    float w1 = ew_s[(size_t)(i+1)*4 + h];
    float w2 = ew_s[(size_t)(i+2)*4 + h];
    float w3 = ew_s[(size_t)(i+3)*4 + h];
    float4 v0 = *(const float4*)(xl + (size_t)s0 * HC + c4*4);
    float4 v1 = *(const float4*)(xl + (size_t)s1 * HC + c4*4);
    float4 v2 = *(const float4*)(xl + (size_t)s2 * HC + c4*4);
    float4 v3 = *(const float4*)(xl + (size_t)s3 * HC + c4*4);
    acc.x += w0*v0.x + w1*v1.x + w2*v2.x + w3*v3.x;
    acc.y += w0*v0.y + w1*v1.y + w2*v2.y + w3*v3.y;
    acc.z += w0*v0.z + w1*v1.z + w2*v2.z + w3*v3.z;
    acc.w += w0*v0.w + w1*v1.w + w2*v2.w + w3*v3.w;
    wsum += w0 + w1 + w2 + w3;
  }
  for (; i < end; ++i) {
    int s = src_s[i];
    float w = ew_s[(size_t)i*4 + h];
    float4 v = *(const float4*)(xl + (size_t)s * HC + c4*4);
    acc.x += w*v.x; acc.y += w*v.y; acc.z += w*v.z; acc.w += w*v.w;
    wsum += w;
  }
  float inv = 1.f / (wsum + 1e-16f);
  float4 b4 = *(const float4*)(bias + c4*4);
  float4 o;
  o.x = acc.x*inv + b4.x; o.y = acc.y*inv + b4.y;
  o.z = acc.z*inv + b4.z; o.w = acc.w*inv + b4.w;
  *(float4*)(outp + (size_t)n * HC + c4*4) = o;
}

__global__ void bn_reduce(const float* __restrict__ A, float* __restrict__ bnsum, float* __restrict__ bnsq)
{
  __shared__ float ss[256], sq[256];
  int t = threadIdx.x;
  int c = t & 127, hh = t >> 7;
  float s = 0.f, q = 0.f;
  for (int n = blockIdx.x * 2 + hh; n < Nn; n += gridDim.x * 2) {
    float v = A[(size_t)n * HC + c];
    s += v; q += v * v;
  }
  ss[t] = s; sq[t] = q;
  __syncthreads();
  if (t < 128) {
    atomicAdd(&bnsum[c], ss[t] + ss[t+128]);
    atomicAdd(&bnsq[c],  sq[t] + sq[t+128]);
  }
}

// global mean pool with BN+ReLU of final layer fused
__global__ void pool_kernel(const float* __restrict__ A, const int* __restrict__ batch,
                            const float* __restrict__ bnsum, const float* __restrict__ bnsq,
                            const float* __restrict__ gammaL, const float* __restrict__ betaL,
                            float* __restrict__ pool)
{
  int t = threadIdx.x;
  int c = t & 127, hh = t >> 7;
  float mu  = bnsum[c] * (1.f / Nn);
  float var = bnsq[c] * (1.f / Nn) - mu * mu;
  float s_ = rsqrtf(var + BN_EPS) * gammaL[c];
  float sh_ = betaL[c] - mu * s_;
  int n0 = blockIdx.x * 256;
  float accv = 0.f; int curg = -1;
  for (int i = hh; i < 256; i += 2) {
    int n = n0 + i;
    if (n >= Nn) break;
    int g = batch[n];
    if (g != curg) {
      if (curg >= 0) atomicAdd(&pool[(size_t)curg * HC + c], accv);
      curg = g; accv = 0.f;
    }
    accv += fmaxf(A[(size_t)n * HC + c] * s_ + sh_, 0.f);
  }
  if (curg >= 0) atomicAdd(&pool[(size_t)curg * HC + c], accv);
}

// batch is sorted: cnt[g] = lower_bound(g+1) - lower_bound(g); fused into FC
__device__ __forceinline__ int lbound(const int* __restrict__ a, int n, int key)
{
  int lo = 0, hi = n;
  while (lo < hi) {
    int mid = (lo + hi) >> 1;
    if (a[mid] < key) lo = mid + 1; else hi = mid;
  }
  return lo;
}

__global__ void final_fc(const float* __restrict__ pool, const int* __restrict__ batch,
                         const float* __restrict__ fcW, const float* __restrict__ fcb,
                         float* __restrict__ out)
{
  int t = blockIdx.x * 256 + threadIdx.x;
  if (t >= Gg * NOUT) return;
  int g = t >> 1, o = t & 1;
  int lo = lbound(batch, Nn, g);
  int hi = lbound(batch, Nn, g + 1);
  float cn = fmaxf((float)(hi - lo), 1.f);
  float acc = 0.f;
  for (int k = 0; k < HC; ++k)
    acc += pool[(size_t)g * HC + k] * fcW[k * NOUT + o];
  out[t] = acc / cn + fcb[o];
}

extern "C" void kernel_launch(void* const* d_in, const int* in_sizes, int n_in,
                              void* d_out, int out_size, void* d_ws, size_t ws_size,
                              hipStream_t stream)
{
  const float* x      = (const float*)d_in[0];
  const int*   eidx   = (const int*)d_in[1];
  const float* eattr  = (const float*)d_in[2];
  const int*   batch  = (const int*)d_in[3];
  const float* efcW   = (const float*)d_in[4];
  const float* efcb   = (const float*)d_in[5];
  const float* Wall   = (const float*)d_in[6];
  const float* attS   = (const float*)d_in[7];
  const float* attD   = (const float*)d_in[8];
  const float* attE   = (const float*)d_in[9];
  const float* linE   = (const float*)d_in[10];
  const float* biases = (const float*)d_in[11];
  const float* gamma  = (const float*)d_in[12];
  const float* beta   = (const float*)d_in[13];
  const float* fcW    = (const float*)d_in[14];
  const float* fcb    = (const float*)d_in[15];
  float* out = (float*)d_out;

  const int* src = eidx;
  const int* dst = eidx + Ee;

  float* ws    = (float*)d_ws;
  float* bufA  = ws;                            // N*128
  float* bufB  = bufA + (size_t)Nn*HC;          // N*128
  float* as_   = bufB + (size_t)Nn*HC;          // N*4
  float* ad_   = as_ + (size_t)Nn*NHD;          // N*4
  float* ew_s  = ad_ + (size_t)Nn*NHD;          // E*4 (16B aligned)
  float* Kmat  = ew_s + (size_t)Ee*NHD;         // 192
  float* kb    = Kmat + 192;                    // 16
  float* bnsum = kb + 16;                       // 128
  float* bnsq  = bnsum + 128;                   // 128
  float* pool  = bnsq + 128;                    // G*128
  int*   rowp  = (int*)(pool + (size_t)Gg*HC);  // N+1
  int*   deg   = rowp + (Nn + 1);               // N
  int*   fill  = deg + Nn;                      // N  (deg..fill one memset)
  int*   src_s = fill + Nn;                     // E
  int*   perm  = src_s + Ee;                    // E
  int*   bsum  = perm + Ee;                     // NSB
  int*   bpre  = bsum + 128;                    // NSB

  compute_K<<<1, 512, 0, stream>>>(efcW, efcb, linE, attE, Kmat, kb);

  // CSR build (reused across all 3 layers)
  hipMemsetAsync(deg, 0, 2*Nn*sizeof(int), stream);
  k_hist<<<(Ee + 255)/256, 256, 0, stream>>>(dst, deg);
  k_bsum<<<NSB, 256, 0, stream>>>(deg, bsum);
  k_mid<<<1, 128, 0, stream>>>(bsum, bpre, rowp);
  k_scan<<<NSB, 256, 0, stream>>>(deg, bpre, rowp);
  k_fill<<<(Ee + 255)/256, 256, 0, stream>>>(src, dst, rowp, fill, src_s, perm);

  for (int l = 0; l < 3; ++l) {
    const float* Ain = (l == 0) ? x : bufA;
    gemm_node<<<((Nn + 127)/128)*2, 256, 0, stream>>>(Ain, Wall + (size_t)l*HC*HC, bufB,
                                                      bnsum, bnsq, gamma + (l-1)*HC, beta + (l-1)*HC,
                                                      (l > 0) ? 1 : 0,
                                                      attS + l*HC, attD + l*HC, as_, ad_);
    edge_alpha<<<(Ee + 255)/256, 256, 0, stream>>>(src, dst, eattr, Kmat, kb, l, as_, ad_, perm, ew_s);
    aggregate<<<(Nn + 7)/8, 256, 0, stream>>>(rowp, src_s, ew_s, bufB, biases + l*HC, bufA);
    hipMemsetAsync(bnsum, 0, 256*sizeof(float), stream);
    bn_reduce<<<256, 256, 0, stream>>>(bufA, bnsum, bnsq);
  }

  hipMemsetAsync(pool, 0, (size_t)Gg*HC*sizeof(float), stream);
  pool_kernel<<<(Nn + 255)/256, 256, 0, stream>>>(bufA, batch, bnsum, bnsq, gamma + 2*HC, beta + 2*HC, pool);
  final_fc<<<2, 256, 0, stream>>>(pool, batch, fcW, fcb, out);
}